// Round 2
// baseline (14689.644 us; speedup 1.0000x reference)
//
#include <hip/hip_runtime.h>
#include <hip/hip_bf16.h>

// -------- VQ-VAE forward, fp32 direct kernels (round 1: ws-size-adaptive) ---
// Round-0 bug: assumed 671 MB of d_ws; never checked ws_size -> device page
// fault (abort). Fix: process batch in chunks of C images, C chosen from
// ws_size at launch (deterministic; same work every call).
// Per-image scratch: h1/d1 slot 2 MB + h2 0.5 MB + ze 0.25 + zq 0.25 + d2 8 MB
//                  = 11,534,336 B.
// Shapes:
//  x        [64,3,128,128]
//  enc1 k4s2p1   3->128 : h1 [C,128,64,64]
//  enc2 k4s2p1 128->128 : h2 [C,128,32,32]
//  enc3 k3s1p1 128->64  : z_e [C,64,32,32]
//  VQ: C*1024 vectors D=64 vs K=512 codes -> z_q
//  dec1 deconv k4s2p1  64->128 : d1 [C,128,64,64] (reuses h1 slot)
//  dec2 deconv k4s2p1 128->128 : d2 [C,128,128,128]
//  dec3 k3s1p1 128->3 : x_recon -> d_out
// Outputs: x_recon (3145728 floats), total_loss, recon_loss, vq_loss

__device__ __forceinline__ float block_reduce_sum(float v) {
  #pragma unroll
  for (int off = 32; off > 0; off >>= 1) v += __shfl_down(v, off, 64);
  __shared__ float s_red[4];
  int lane = threadIdx.x & 63;
  int wid  = threadIdx.x >> 6;
  if (lane == 0) s_red[wid] = v;
  __syncthreads();
  float r = 0.f;
  if (threadIdx.x == 0) r = s_red[0] + s_red[1] + s_red[2] + s_red[3];
  return r;
}

// ---------------- conv1: x[C,3,128,128] -> h1[C,128,64,64], k4 s2 p1, ReLU
__global__ __launch_bounds__(256) void conv1_k(
    const float* __restrict__ x, const float* __restrict__ w,
    const float* __restrict__ b, float* __restrict__ out) {
  int i = blockIdx.x * 256 + threadIdx.x;           // C*128*64*64 threads
  int ow = i & 63; int t = i >> 6;
  int oh = t & 63; t >>= 6;
  int co = t & 127; int n = t >> 7;
  float acc = b[co];
  const float* wp = w + co * 48;                    // [co][ci][4][4]
  #pragma unroll
  for (int ci = 0; ci < 3; ++ci) {
    const float* xp = x + (n * 3 + ci) * 16384;
    #pragma unroll
    for (int kh = 0; kh < 4; ++kh) {
      int ih = 2 * oh - 1 + kh;
      if ((unsigned)ih < 128u) {
        #pragma unroll
        for (int kw = 0; kw < 4; ++kw) {
          int iw = 2 * ow - 1 + kw;
          if ((unsigned)iw < 128u)
            acc = fmaf(xp[ih * 128 + iw], wp[ci * 16 + kh * 4 + kw], acc);
        }
      }
    }
  }
  out[i] = fmaxf(acc, 0.f);
}

// ---------------- conv2: h1 -> h2[C,128,32,32], k4 s2 p1, ReLU
__global__ __launch_bounds__(256) void conv2_k(
    const float* __restrict__ in, const float* __restrict__ w,
    const float* __restrict__ b, float* __restrict__ out) {
  int n = blockIdx.y;
  int co0 = blockIdx.x * 8;
  __shared__ float s_in[66 * 66];
  __shared__ float s_w[128];
  int tid = threadIdx.x;
  float acc[4][8];
  #pragma unroll
  for (int j = 0; j < 4; ++j)
    #pragma unroll
    for (int c = 0; c < 8; ++c) acc[j][c] = 0.f;
  int oh[4], ow[4];
  #pragma unroll
  for (int j = 0; j < 4; ++j) { int p = tid + 256 * j; oh[j] = p >> 5; ow[j] = p & 31; }
  int wco = tid >> 4, wtap = tid & 15;
  for (int ci = 0; ci < 128; ++ci) {
    __syncthreads();
    const float* ip = in + (n * 128 + ci) * 4096;
    for (int t = tid; t < 66 * 66; t += 256) {
      int r = t / 66, c = t - r * 66;
      int ih = r - 1, iw = c - 1;
      float v = 0.f;
      if ((unsigned)ih < 64u && (unsigned)iw < 64u) v = ip[ih * 64 + iw];
      s_in[t] = v;
    }
    if (tid < 128) s_w[tid] = w[((co0 + wco) * 128 + ci) * 16 + wtap];
    __syncthreads();
    #pragma unroll
    for (int kh = 0; kh < 4; ++kh) {
      #pragma unroll
      for (int kw = 0; kw < 4; ++kw) {
        float iv[4];
        #pragma unroll
        for (int j = 0; j < 4; ++j)
          iv[j] = s_in[(2 * oh[j] + kh) * 66 + 2 * ow[j] + kw];
        #pragma unroll
        for (int co = 0; co < 8; ++co) {
          float wv = s_w[co * 16 + kh * 4 + kw];
          #pragma unroll
          for (int j = 0; j < 4; ++j) acc[j][co] = fmaf(iv[j], wv, acc[j][co]);
        }
      }
    }
  }
  #pragma unroll
  for (int co = 0; co < 8; ++co) {
    float bias = b[co0 + co];
    #pragma unroll
    for (int j = 0; j < 4; ++j) {
      float v = fmaxf(acc[j][co] + bias, 0.f);
      out[((n * 128 + co0 + co) * 32 + oh[j]) * 32 + ow[j]] = v;
    }
  }
}

// ---------------- conv3: h2 -> z_e[C,64,32,32], k3 s1 p1, NO relu
__global__ __launch_bounds__(256) void conv3_k(
    const float* __restrict__ in, const float* __restrict__ w,
    const float* __restrict__ b, float* __restrict__ out) {
  int n = blockIdx.y;
  int co0 = blockIdx.x * 8;
  __shared__ float s_in[34 * 34];
  __shared__ float s_w[72];
  int tid = threadIdx.x;
  float acc[4][8];
  #pragma unroll
  for (int j = 0; j < 4; ++j)
    #pragma unroll
    for (int c = 0; c < 8; ++c) acc[j][c] = 0.f;
  int oh[4], ow[4];
  #pragma unroll
  for (int j = 0; j < 4; ++j) { int p = tid + 256 * j; oh[j] = p >> 5; ow[j] = p & 31; }
  int wco = tid / 9, wtap = tid - wco * 9;
  for (int ci = 0; ci < 128; ++ci) {
    __syncthreads();
    const float* ip = in + (n * 128 + ci) * 1024;
    for (int t = tid; t < 34 * 34; t += 256) {
      int r = t / 34, c = t - r * 34;
      int ih = r - 1, iw = c - 1;
      float v = 0.f;
      if ((unsigned)ih < 32u && (unsigned)iw < 32u) v = ip[ih * 32 + iw];
      s_in[t] = v;
    }
    if (tid < 72) s_w[tid] = w[((co0 + wco) * 128 + ci) * 9 + wtap];
    __syncthreads();
    #pragma unroll
    for (int kh = 0; kh < 3; ++kh) {
      #pragma unroll
      for (int kw = 0; kw < 3; ++kw) {
        float iv[4];
        #pragma unroll
        for (int j = 0; j < 4; ++j)
          iv[j] = s_in[(oh[j] + kh) * 34 + ow[j] + kw];
        #pragma unroll
        for (int co = 0; co < 8; ++co) {
          float wv = s_w[co * 9 + kh * 3 + kw];
          #pragma unroll
          for (int j = 0; j < 4; ++j) acc[j][co] = fmaf(iv[j], wv, acc[j][co]);
        }
      }
    }
  }
  #pragma unroll
  for (int co = 0; co < 8; ++co) {
    float bias = b[co0 + co];
    #pragma unroll
    for (int j = 0; j < 4; ++j)
      out[((n * 64 + co0 + co) * 32 + oh[j]) * 32 + ow[j]] = acc[j][co] + bias;
  }
}

// ---------------- VQ: z_e -> z_q, accumulate sum((z_e-z_q)^2)
__global__ __launch_bounds__(256) void vq_k(
    const float* __restrict__ ze, const float* __restrict__ cb,
    float* __restrict__ zq, float* __restrict__ acc_loss) {
  __shared__ float s_cb[128 * 64];
  __shared__ float s_norm[128];
  int tid = threadIdx.x;
  int p = blockIdx.x * 256 + tid;         // 0..C*1024-1
  int n = p >> 10, pos = p & 1023;
  const float* zp = ze + n * 65536 + pos;
  float z[64];
  #pragma unroll
  for (int d = 0; d < 64; ++d) z[d] = zp[d * 1024];
  float best = 3.4e38f;
  int bidx = 0;
  for (int ch = 0; ch < 4; ++ch) {
    __syncthreads();
    for (int t = tid; t < 8192; t += 256) s_cb[t] = cb[ch * 8192 + t];
    __syncthreads();
    if (tid < 128) {
      float nn = 0.f;
      #pragma unroll
      for (int d = 0; d < 64; ++d) nn = fmaf(s_cb[tid * 64 + d], s_cb[tid * 64 + d], nn);
      s_norm[tid] = nn;
    }
    __syncthreads();
    for (int k = 0; k < 128; ++k) {
      float dot = 0.f;
      #pragma unroll
      for (int d = 0; d < 64; ++d) dot = fmaf(z[d], s_cb[k * 64 + d], dot);
      float dist = s_norm[k] - 2.0f * dot;   // + ||z||^2 is row-constant
      if (dist < best) { best = dist; bidx = ch * 128 + k; }
    }
  }
  float lsum = 0.f;
  const float4* crow = (const float4*)(cb + bidx * 64);
  float* zqp = zq + n * 65536 + pos;
  #pragma unroll
  for (int q = 0; q < 16; ++q) {
    float4 c4 = crow[q];
    int d = q * 4;
    zqp[(d + 0) * 1024] = c4.x;
    zqp[(d + 1) * 1024] = c4.y;
    zqp[(d + 2) * 1024] = c4.z;
    zqp[(d + 3) * 1024] = c4.w;
    float df;
    df = z[d + 0] - c4.x; lsum = fmaf(df, df, lsum);
    df = z[d + 1] - c4.y; lsum = fmaf(df, df, lsum);
    df = z[d + 2] - c4.z; lsum = fmaf(df, df, lsum);
    df = z[d + 3] - c4.w; lsum = fmaf(df, df, lsum);
  }
  float bs = block_reduce_sum(lsum);
  if (tid == 0) atomicAdd(acc_loss, bs);
}

// ---------------- deconv1: z_q[C,64,32,32] -> d1[C,128,64,64], k4 s2 p1, ReLU
// parity decomposition: class (a,b); per class 2x2 taps (kh = oh - 2*ih + 1).
__global__ __launch_bounds__(256) void deconv1_k(
    const float* __restrict__ in, const float* __restrict__ w,
    const float* __restrict__ b, float* __restrict__ out) {
  const int CI = 64, CO = 128;
  int n = blockIdx.z;
  int cls = blockIdx.y;
  int co0 = blockIdx.x * 8;
  int a = cls >> 1, bb = cls & 1;
  int kh0 = a ? 0 : 1, kh1 = a ? 2 : 3;
  int dih0 = a ? 1 : 0, dih1 = a ? 0 : -1;
  int kw0 = bb ? 0 : 1, kw1 = bb ? 2 : 3;
  int djw0 = bb ? 1 : 0, djw1 = bb ? 0 : -1;
  __shared__ float s_in[34 * 34];
  __shared__ float s_w[32];
  int tid = threadIdx.x;
  float acc[4][8];
  #pragma unroll
  for (int j = 0; j < 4; ++j)
    #pragma unroll
    for (int c = 0; c < 8; ++c) acc[j][c] = 0.f;
  int hh[4], ww[4];
  #pragma unroll
  for (int j = 0; j < 4; ++j) { int p = tid + 256 * j; hh[j] = p >> 5; ww[j] = p & 31; }
  for (int ci = 0; ci < CI; ++ci) {
    __syncthreads();
    const float* ip = in + (n * CI + ci) * 1024;
    for (int t = tid; t < 34 * 34; t += 256) {
      int r = t / 34, c = t - r * 34;
      int ih = r - 1, iw = c - 1;
      float v = 0.f;
      if ((unsigned)ih < 32u && (unsigned)iw < 32u) v = ip[ih * 32 + iw];
      s_in[t] = v;
    }
    if (tid < 32) {
      int co_l = tid >> 2, i = (tid >> 1) & 1, jj = tid & 1;
      int kh = i ? kh1 : kh0, kw = jj ? kw1 : kw0;
      s_w[tid] = w[((ci * CO + co0 + co_l) * 4 + kh) * 4 + kw];
    }
    __syncthreads();
    #pragma unroll
    for (int i = 0; i < 2; ++i) {
      int dih = i ? dih1 : dih0;
      #pragma unroll
      for (int jj = 0; jj < 2; ++jj) {
        int djw = jj ? djw1 : djw0;
        float iv[4];
        #pragma unroll
        for (int j = 0; j < 4; ++j)
          iv[j] = s_in[(hh[j] + dih + 1) * 34 + (ww[j] + djw + 1)];
        #pragma unroll
        for (int co = 0; co < 8; ++co) {
          float wv = s_w[co * 4 + i * 2 + jj];
          #pragma unroll
          for (int j = 0; j < 4; ++j) acc[j][co] = fmaf(iv[j], wv, acc[j][co]);
        }
      }
    }
  }
  #pragma unroll
  for (int co = 0; co < 8; ++co) {
    float bias = b[co0 + co];
    #pragma unroll
    for (int j = 0; j < 4; ++j) {
      int oh = 2 * hh[j] + a, ow = 2 * ww[j] + bb;
      float v = fmaxf(acc[j][co] + bias, 0.f);
      out[((n * CO + co0 + co) * 64 + oh) * 64 + ow] = v;
    }
  }
}

// ---------------- deconv2: d1[C,128,64,64] -> d2[C,128,128,128], k4 s2 p1, ReLU
__global__ __launch_bounds__(256) void deconv2_k(
    const float* __restrict__ in, const float* __restrict__ w,
    const float* __restrict__ b, float* __restrict__ out) {
  const int CI = 128, CO = 128;
  int n = blockIdx.z;
  int cls = blockIdx.y >> 1;
  int half = blockIdx.y & 1;
  int co0 = blockIdx.x * 8;
  int r0 = half * 32;
  int a = cls >> 1, bb = cls & 1;
  int kh0 = a ? 0 : 1, kh1 = a ? 2 : 3;
  int dih0 = a ? 1 : 0, dih1 = a ? 0 : -1;
  int kw0 = bb ? 0 : 1, kw1 = bb ? 2 : 3;
  int djw0 = bb ? 1 : 0, djw1 = bb ? 0 : -1;
  __shared__ float s_in[34 * 66];
  __shared__ float s_w[32];
  int tid = threadIdx.x;
  float acc[8][8];
  #pragma unroll
  for (int j = 0; j < 8; ++j)
    #pragma unroll
    for (int c = 0; c < 8; ++c) acc[j][c] = 0.f;
  int hrow = tid >> 6;            // 0..3
  int ww = tid & 63;
  for (int ci = 0; ci < CI; ++ci) {
    __syncthreads();
    const float* ip = in + (n * CI + ci) * 4096;
    for (int t = tid; t < 34 * 66; t += 256) {
      int r = t / 66, c = t - r * 66;
      int ih = r0 - 1 + r, iw = c - 1;
      float v = 0.f;
      if ((unsigned)ih < 64u && (unsigned)iw < 64u) v = ip[ih * 64 + iw];
      s_in[t] = v;
    }
    if (tid < 32) {
      int co_l = tid >> 2, i = (tid >> 1) & 1, jj = tid & 1;
      int kh = i ? kh1 : kh0, kw = jj ? kw1 : kw0;
      s_w[tid] = w[((ci * CO + co0 + co_l) * 4 + kh) * 4 + kw];
    }
    __syncthreads();
    #pragma unroll
    for (int i = 0; i < 2; ++i) {
      int dih = i ? dih1 : dih0;
      #pragma unroll
      for (int jj = 0; jj < 2; ++jj) {
        int djw = jj ? djw1 : djw0;
        float iv[8];
        #pragma unroll
        for (int j = 0; j < 8; ++j)
          iv[j] = s_in[(hrow + 4 * j + dih + 1) * 66 + (ww + djw + 1)];
        #pragma unroll
        for (int co = 0; co < 8; ++co) {
          float wv = s_w[co * 4 + i * 2 + jj];
          #pragma unroll
          for (int j = 0; j < 8; ++j) acc[j][co] = fmaf(iv[j], wv, acc[j][co]);
        }
      }
    }
  }
  #pragma unroll
  for (int co = 0; co < 8; ++co) {
    float bias = b[co0 + co];
    #pragma unroll
    for (int j = 0; j < 8; ++j) {
      int hh = r0 + hrow + 4 * j;
      int oh = 2 * hh + a, ow = 2 * ww + bb;
      float v = fmaxf(acc[j][co] + bias, 0.f);
      out[((n * CO + co0 + co) * 128 + oh) * 128 + ow] = v;
    }
  }
}

// ---------------- conv4: d2 -> x_recon (d_out), k3 s1 p1, no relu, + recon loss
__global__ __launch_bounds__(256) void conv4_k(
    const float* __restrict__ in, const float* __restrict__ w,
    const float* __restrict__ b, const float* __restrict__ x,
    float* __restrict__ out, float* __restrict__ acc_loss) {
  int n = blockIdx.y;
  int r0 = blockIdx.x * 16;
  __shared__ float s_in[18 * 130];
  __shared__ float s_w[27];
  int tid = threadIdx.x;
  float acc[8][3];
  #pragma unroll
  for (int j = 0; j < 8; ++j)
    #pragma unroll
    for (int c = 0; c < 3; ++c) acc[j][c] = 0.f;
  int rr = tid >> 7;             // 0..1
  int cc = tid & 127;
  int wco = tid / 9, wtap = tid - wco * 9;
  for (int ci = 0; ci < 128; ++ci) {
    __syncthreads();
    const float* ip = in + (n * 128 + ci) * 16384;
    for (int t = tid; t < 18 * 130; t += 256) {
      int r = t / 130, c = t - r * 130;
      int ih = r0 - 1 + r, iw = c - 1;
      float v = 0.f;
      if ((unsigned)ih < 128u && (unsigned)iw < 128u) v = ip[ih * 128 + iw];
      s_in[t] = v;
    }
    if (tid < 27) s_w[tid] = w[(wco * 128 + ci) * 9 + wtap];
    __syncthreads();
    #pragma unroll
    for (int kh = 0; kh < 3; ++kh) {
      #pragma unroll
      for (int kw = 0; kw < 3; ++kw) {
        float iv[8];
        #pragma unroll
        for (int j = 0; j < 8; ++j)
          iv[j] = s_in[(rr + 2 * j + kh) * 130 + cc + kw];
        #pragma unroll
        for (int co = 0; co < 3; ++co) {
          float wv = s_w[co * 9 + kh * 3 + kw];
          #pragma unroll
          for (int j = 0; j < 8; ++j) acc[j][co] = fmaf(iv[j], wv, acc[j][co]);
        }
      }
    }
  }
  float lsum = 0.f;
  #pragma unroll
  for (int j = 0; j < 8; ++j) {
    int oh = r0 + rr + 2 * j;
    #pragma unroll
    for (int co = 0; co < 3; ++co) {
      float v = acc[j][co] + b[co];
      int gi = ((n * 3 + co) * 128 + oh) * 128 + cc;
      out[gi] = v;
      float d = v - x[gi];
      lsum = fmaf(d, d, lsum);
    }
  }
  float bs = block_reduce_sum(lsum);
  if (tid == 0) atomicAdd(acc_loss, bs);
}

// ---------------- finalize losses (full-batch divisors; acc spans all chunks)
__global__ void finalize_k(const float* __restrict__ accv, float* __restrict__ out) {
  if (threadIdx.x == 0 && blockIdx.x == 0) {
    float recon = accv[0] / 3145728.0f;
    float vq = 1.25f * accv[1] / 4194304.0f;
    out[3145728] = recon + vq;
    out[3145729] = recon;
    out[3145730] = vq;
  }
}

extern "C" void kernel_launch(void* const* d_in, const int* in_sizes, int n_in,
                              void* d_out, int out_size, void* d_ws, size_t ws_size,
                              hipStream_t stream) {
  const float* x   = (const float*)d_in[0];
  const float* ew1 = (const float*)d_in[1];
  const float* eb1 = (const float*)d_in[2];
  const float* ew2 = (const float*)d_in[3];
  const float* eb2 = (const float*)d_in[4];
  const float* ew3 = (const float*)d_in[5];
  const float* eb3 = (const float*)d_in[6];
  const float* cb  = (const float*)d_in[7];
  const float* dw1 = (const float*)d_in[8];
  const float* db1 = (const float*)d_in[9];
  const float* dw2 = (const float*)d_in[10];
  const float* db2 = (const float*)d_in[11];
  const float* dw3 = (const float*)d_in[12];
  const float* db3 = (const float*)d_in[13];
  float* out = (float*)d_out;

  // ---- choose chunk size C from ws_size (constant across calls) ----
  const size_t PER_IMG = 11534336ull;   // bytes of scratch per image
  int C = 64;
  while (C > 1 && 256ull + PER_IMG * (size_t)C > ws_size) C >>= 1;

  char* ws = (char*)d_ws;
  float* acc = (float*)ws;              // acc[0]=recon ss, acc[1]=vq ss
  char* p = ws + 256;
  float* h1 = (float*)p;  p += (size_t)C * 2097152ull;   // h1 / d1 slot
  float* h2 = (float*)p;  p += (size_t)C * 524288ull;
  float* ze = (float*)p;  p += (size_t)C * 262144ull;
  float* zq = (float*)p;  p += (size_t)C * 262144ull;
  float* d2 = (float*)p;                                  // C * 8,388,608 B

  hipMemsetAsync(acc, 0, 256, stream);
  for (int n0 = 0; n0 < 64; n0 += C) {
    const float* xc = x + (size_t)n0 * 49152;
    float* oc = out + (size_t)n0 * 49152;
    conv1_k<<<C * 2048, 256, 0, stream>>>(xc, ew1, eb1, h1);
    conv2_k<<<dim3(16, C), 256, 0, stream>>>(h1, ew2, eb2, h2);
    conv3_k<<<dim3(8, C), 256, 0, stream>>>(h2, ew3, eb3, ze);
    vq_k<<<C * 4, 256, 0, stream>>>(ze, cb, zq, acc + 1);
    deconv1_k<<<dim3(16, 4, C), 256, 0, stream>>>(zq, dw1, db1, h1);
    deconv2_k<<<dim3(16, 8, C), 256, 0, stream>>>(h1, dw2, db2, d2);
    conv4_k<<<dim3(8, C), 256, 0, stream>>>(d2, dw3, db3, xc, oc, acc);
  }
  finalize_k<<<1, 64, 0, stream>>>(acc, out);
}

// Round 3
// 2169.062 us; speedup vs baseline: 6.7723x; 6.7723x over previous
//
#include <hip/hip_runtime.h>
#include <hip/hip_bf16.h>

// ---- VQ-VAE forward, round 3: bf16 MFMA implicit-GEMM, NHWC intermediates --
// All heavy convs -> v_mfma_f32_32x32x16_bf16. Wave computes M=32 output
// positions x N=32*NT co. A-frag: 8 contiguous ci from NHWC activations
// (16B load, zero-page pointer select for padding). B-frag: weights repacked
// per-call into fragment order [cls][tap][kc][nt][lane*8+j] (16B coalesced).
// Layout facts (HW-verified per guide): 32x32x16_bf16
//   A[m=lane&31][k=(lane>>5)*8+j], B[k=(lane>>5)*8+j][n=lane&31],
//   D: col(n)=lane&31, row(m)=(reg&3)+8*(reg>>2)+4*(lane>>5).
// Deconv k4s2p1 parity class (a,b): out(2q+a,2r+b) += in(q+a-i, r+b-j) *
//   w[ci][co][2i+1-a][2j+1-b]  (i,j in {0,1})  -- verified in round 2.

typedef __attribute__((ext_vector_type(8))) short short8;
typedef __attribute__((ext_vector_type(16))) float f32x16;

__device__ __forceinline__ unsigned short f2bf(float f) {
  union { __hip_bfloat16 b; unsigned short u; } cv;
  cv.b = __float2bfloat16(f);
  return cv.u;
}
__device__ __forceinline__ unsigned pack2bf(float a, float b) {
  return (unsigned)f2bf(a) | ((unsigned)f2bf(b) << 16);
}

__device__ __forceinline__ float block_reduce_sum(float v) {
  #pragma unroll
  for (int off = 32; off > 0; off >>= 1) v += __shfl_down(v, off, 64);
  __shared__ float s_red[4];
  int lane = threadIdx.x & 63;
  int wid  = threadIdx.x >> 6;
  if (lane == 0) s_red[wid] = v;
  __syncthreads();
  float r = 0.f;
  if (threadIdx.x == 0) r = s_red[0] + s_red[1] + s_red[2] + s_red[3];
  return r;
}

// ---------------- weight repack: conv layers  w[CO][CI][NTAP] fp32 -> frags
template<int CI, int NTAP, int NT>
__global__ void repack_conv_w(const float* __restrict__ w,
                              unsigned short* __restrict__ wb, int co_real) {
  const int KC = CI / 16;
  const int total = NTAP * KC * NT * 512;
  int i = blockIdx.x * 256 + threadIdx.x;
  if (i >= total) return;
  int j = i & 7, lane = (i >> 3) & 63, t2 = i >> 9;
  int nt = t2 % NT; t2 /= NT;
  int kc = t2 % KC; int tap = t2 / KC;
  int co = nt * 32 + (lane & 31);
  int ci = kc * 16 + (lane >> 5) * 8 + j;
  float v = (co < co_real) ? w[(co * CI + ci) * NTAP + tap] : 0.f;
  wb[i] = f2bf(v);
}

// ---------------- weight repack: deconv  w[CI][CO][4][4] fp32 -> frags/class
template<int CI, int CO, int NT>
__global__ void repack_deconv_w(const float* __restrict__ w,
                                unsigned short* __restrict__ wb) {
  const int KC = CI / 16;
  const int total = 16 * KC * NT * 512;   // 4 cls * 4 taps
  int i = blockIdx.x * 256 + threadIdx.x;
  if (i >= total) return;
  int j = i & 7, lane = (i >> 3) & 63, t2 = i >> 9;
  int nt = t2 % NT; t2 /= NT;
  int kc = t2 % KC; t2 /= KC;
  int tap = t2 & 3, cls = t2 >> 2;
  int a = cls >> 1, b = cls & 1, ti = tap >> 1, tj = tap & 1;
  int kh = 2 * ti + 1 - a, kw = 2 * tj + 1 - b;
  int co = nt * 32 + (lane & 31);
  int ci = kc * 16 + (lane >> 5) * 8 + j;
  wb[i] = f2bf(w[((ci * CO + co) * 4 + kh) * 4 + kw]);
}

// ---------------- conv1: x NCHW fp32 [C,3,128,128] -> h1 NHWC bf16 [C,64,64,128]
// k4 s2 p1, ReLU. K=48 too small for MFMA; LDS-staged VALU.
__global__ __launch_bounds__(256) void conv1_k(
    const float* __restrict__ x, const float* __restrict__ w,
    const float* __restrict__ bias, unsigned short* __restrict__ out) {
  __shared__ float sw[48 * 128];   // [tap][co]
  __shared__ float sx[3 * 4 * 18]; // [ci][kh][col]
  int tid = threadIdx.x;
  int n = blockIdx.x >> 9, rr = blockIdx.x & 511;
  int oh = rr >> 3, ow0 = (rr & 7) * 8;
  for (int i = tid; i < 6144; i += 256) {
    int tap = i >> 7, co = i & 127;
    sw[i] = w[co * 48 + tap];
  }
  for (int i = tid; i < 216; i += 256) {
    int ci = i / 72, r = i % 72, kh = r / 18, c = r % 18;
    int ih = 2 * oh - 1 + kh, iw = 2 * ow0 - 1 + c;
    float v = 0.f;
    if ((unsigned)ih < 128u && (unsigned)iw < 128u)
      v = x[(n * 3 + ci) * 16384 + ih * 128 + iw];
    sx[i] = v;
  }
  __syncthreads();
  int p = tid >> 5, co0 = (tid & 31) * 4;
  float xv[48];
  #pragma unroll
  for (int ci = 0; ci < 3; ++ci)
    #pragma unroll
    for (int kh = 0; kh < 4; ++kh)
      #pragma unroll
      for (int kw = 0; kw < 4; ++kw)
        xv[ci * 16 + kh * 4 + kw] = sx[ci * 72 + kh * 18 + 2 * p + kw];
  float a0 = bias[co0], a1 = bias[co0 + 1], a2 = bias[co0 + 2], a3 = bias[co0 + 3];
  #pragma unroll
  for (int tap = 0; tap < 48; ++tap) {
    float4 w4 = *(const float4*)&sw[tap * 128 + co0];
    a0 = fmaf(xv[tap], w4.x, a0);
    a1 = fmaf(xv[tap], w4.y, a1);
    a2 = fmaf(xv[tap], w4.z, a2);
    a3 = fmaf(xv[tap], w4.w, a3);
  }
  a0 = fmaxf(a0, 0.f); a1 = fmaxf(a1, 0.f); a2 = fmaxf(a2, 0.f); a3 = fmaxf(a3, 0.f);
  uint2 u; u.x = pack2bf(a0, a1); u.y = pack2bf(a2, a3);
  *(uint2*)(out + ((n * 64 + oh) * 64 + ow0 + p) * 128 + co0) = u;
}

// ---------------- generic MFMA conv / parity-deconv
// in: NHWC bf16 [C,IH,IW,CI]; out: NHWC [C,OHf,OWf,CO] (deconv: OHf=2*OH)
// M-tile 128/block (4 waves x 32), N = 32*NT per wave, K = NTAP*CI.
template<int CI, int CO, int NT, int IH, int IW, int OH, int OW, int NTAP,
         int KW, int STRIDE, bool DECONV, bool RELU, bool F32OUT>
__global__ __launch_bounds__(256, 3) void mconv_k(
    const unsigned short* __restrict__ in, const unsigned short* __restrict__ wb,
    const float* __restrict__ bias, void* __restrict__ outv,
    const unsigned short* __restrict__ zeropg) {
  const int KC = CI / 16;
  int lane = threadIdx.x & 63, wv = threadIdx.x >> 6;
  int m0 = blockIdx.x * 128 + wv * 32;
  int mm = m0 + (lane & 31);
  int n = mm / (OH * OW), rem = mm % (OH * OW);
  int oh = rem / OW, ow = rem % OW;
  int cls = DECONV ? blockIdx.y : 0;
  int ca = cls >> 1, cb2 = cls & 1;
  int khalf = lane >> 5;
  f32x16 acc[NT];
  #pragma unroll
  for (int t = 0; t < NT; ++t)
    #pragma unroll
    for (int e = 0; e < 16; ++e) acc[t][e] = 0.f;
  const unsigned short* wbc = wb + cls * (NTAP * KC * NT * 512);
  #pragma unroll
  for (int t = 0; t < NTAP; ++t) {
    int ih, iw;
    if (DECONV) { ih = oh + ca - (t >> 1); iw = ow + cb2 - (t & 1); }
    else        { ih = STRIDE * oh - 1 + t / KW; iw = STRIDE * ow - 1 + t % KW; }
    bool valid = ((unsigned)ih < (unsigned)IH) && ((unsigned)iw < (unsigned)IW);
    const unsigned short* ap =
        valid ? (in + ((n * IH + ih) * IW + iw) * CI + khalf * 8)
              : (zeropg + khalf * 8);
    const unsigned short* bp = wbc + t * (KC * NT * 512) + lane * 8;
    #pragma unroll
    for (int kc = 0; kc < KC; ++kc) {
      short8 af = *(const short8*)(ap + kc * 16);
      #pragma unroll
      for (int nt = 0; nt < NT; ++nt) {
        short8 bf_ = *(const short8*)(bp + (kc * NT + nt) * 512);
        acc[nt] = __builtin_amdgcn_mfma_f32_32x32x16_bf16(af, bf_, acc[nt], 0, 0, 0);
      }
    }
  }
  int col = lane & 31;
  #pragma unroll
  for (int nt = 0; nt < NT; ++nt) {
    int co = nt * 32 + col;
    float bv = bias[co];
    #pragma unroll
    for (int r = 0; r < 16; ++r) {
      int mrow = (r & 3) + 8 * (r >> 2) + 4 * khalf;
      int mp = m0 + mrow;
      int n2 = mp / (OH * OW), r2 = mp % (OH * OW);
      int oh2 = r2 / OW, ow2 = r2 % OW;
      float v = acc[nt][r] + bv;
      if (RELU) v = fmaxf(v, 0.f);
      int idx;
      if (DECONV)
        idx = ((n2 * (2 * OH) + 2 * oh2 + ca) * (2 * OW) + 2 * ow2 + cb2) * CO + co;
      else
        idx = ((n2 * OH + oh2) * OW + ow2) * CO + co;
      if (F32OUT) ((float*)outv)[idx] = v;
      else        ((unsigned short*)outv)[idx] = f2bf(v);
    }
  }
}

// ---------------- VQ: ze fp32 [P,64] -> zq bf16 [P,64], vq ss (fp32)
__global__ __launch_bounds__(256) void vq_k(
    const float* __restrict__ ze, const float* __restrict__ cb,
    unsigned short* __restrict__ zq, float* __restrict__ acc_loss) {
  __shared__ float s_cb[8192];
  __shared__ float s_norm[128];
  int tid = threadIdx.x;
  int p = blockIdx.x * 256 + tid;
  const float4* zp = (const float4*)(ze + (size_t)p * 64);
  float z[64];
  #pragma unroll
  for (int q = 0; q < 16; ++q) {
    float4 v = zp[q];
    z[4 * q] = v.x; z[4 * q + 1] = v.y; z[4 * q + 2] = v.z; z[4 * q + 3] = v.w;
  }
  float best = 3.4e38f;
  int bidx = 0;
  for (int ch = 0; ch < 4; ++ch) {
    __syncthreads();
    for (int t = tid; t < 8192; t += 256) s_cb[t] = cb[ch * 8192 + t];
    __syncthreads();
    if (tid < 128) {
      float nn = 0.f;
      #pragma unroll
      for (int d = 0; d < 64; ++d) nn = fmaf(s_cb[tid * 64 + d], s_cb[tid * 64 + d], nn);
      s_norm[tid] = nn;
    }
    __syncthreads();
    for (int k = 0; k < 128; ++k) {
      float dot = 0.f;
      #pragma unroll
      for (int d = 0; d < 64; ++d) dot = fmaf(z[d], s_cb[k * 64 + d], dot);
      float dist = s_norm[k] - 2.0f * dot;   // + ||z||^2 is row-constant
      if (dist < best) { best = dist; bidx = ch * 128 + k; }
    }
  }
  float lsum = 0.f;
  const float4* crow = (const float4*)(cb + bidx * 64);
  unsigned* zqp = (unsigned*)(zq + (size_t)p * 64);
  #pragma unroll
  for (int q = 0; q < 16; ++q) {
    float4 c4 = crow[q];
    zqp[2 * q]     = pack2bf(c4.x, c4.y);
    zqp[2 * q + 1] = pack2bf(c4.z, c4.w);
    float df;
    df = z[4 * q]     - c4.x; lsum = fmaf(df, df, lsum);
    df = z[4 * q + 1] - c4.y; lsum = fmaf(df, df, lsum);
    df = z[4 * q + 2] - c4.z; lsum = fmaf(df, df, lsum);
    df = z[4 * q + 3] - c4.w; lsum = fmaf(df, df, lsum);
  }
  float bs = block_reduce_sum(lsum);
  if (tid == 0) atomicAdd(acc_loss, bs);
}

// ---------------- conv4: d2 NHWC bf16 -> x_recon NCHW fp32 (+recon loss)
// k3 s1 p1, CO=3 padded to N=32 (NT=1), fused loss.
__global__ __launch_bounds__(256, 3) void conv4_k(
    const unsigned short* __restrict__ in, const unsigned short* __restrict__ wb,
    const float* __restrict__ bias, const float* __restrict__ x,
    float* __restrict__ out, float* __restrict__ acc_loss,
    const unsigned short* __restrict__ zeropg) {
  int lane = threadIdx.x & 63, wv = threadIdx.x >> 6;
  int m0 = blockIdx.x * 128 + wv * 32;
  int mm = m0 + (lane & 31);
  int n = mm >> 14, rem = mm & 16383;
  int oh = rem >> 7, ow = rem & 127;
  int khalf = lane >> 5;
  f32x16 acc;
  #pragma unroll
  for (int e = 0; e < 16; ++e) acc[e] = 0.f;
  #pragma unroll
  for (int t = 0; t < 9; ++t) {
    int ih = oh - 1 + t / 3, iw = ow - 1 + t % 3;
    bool valid = ((unsigned)ih < 128u) && ((unsigned)iw < 128u);
    const unsigned short* ap =
        valid ? (in + ((n * 128 + ih) * 128 + iw) * 128 + khalf * 8)
              : (zeropg + khalf * 8);
    const unsigned short* bp = wb + t * (8 * 512) + lane * 8;
    #pragma unroll
    for (int kc = 0; kc < 8; ++kc) {
      short8 af = *(const short8*)(ap + kc * 16);
      short8 bf_ = *(const short8*)(bp + kc * 512);
      acc = __builtin_amdgcn_mfma_f32_32x32x16_bf16(af, bf_, acc, 0, 0, 0);
    }
  }
  int co = lane & 31;
  float bv = (co < 3) ? bias[co] : 0.f;
  float lsum = 0.f;
  #pragma unroll
  for (int r = 0; r < 16; ++r) {
    int mrow = (r & 3) + 8 * (r >> 2) + 4 * khalf;
    int mp = m0 + mrow;
    int n2 = mp >> 14, r2 = mp & 16383;
    float v = acc[r] + bv;
    if (co < 3) {
      int gi = (n2 * 3 + co) * 16384 + r2;
      out[gi] = v;
      float d = v - x[gi];
      lsum = fmaf(d, d, lsum);
    }
  }
  #pragma unroll
  for (int off = 32; off > 0; off >>= 1) lsum += __shfl_down(lsum, off, 64);
  if (lane == 0) atomicAdd(acc_loss, lsum);
}

// ---------------- finalize losses
__global__ void finalize_k(const float* __restrict__ accv, float* __restrict__ out) {
  if (threadIdx.x == 0 && blockIdx.x == 0) {
    float recon = accv[0] / 3145728.0f;
    float vq = 1.25f * accv[1] / 4194304.0f;
    out[3145728] = recon + vq;
    out[3145729] = recon;
    out[3145730] = vq;
  }
}

extern "C" void kernel_launch(void* const* d_in, const int* in_sizes, int n_in,
                              void* d_out, int out_size, void* d_ws, size_t ws_size,
                              hipStream_t stream) {
  const float* x   = (const float*)d_in[0];
  const float* ew1 = (const float*)d_in[1];
  const float* eb1 = (const float*)d_in[2];
  const float* ew2 = (const float*)d_in[3];
  const float* eb2 = (const float*)d_in[4];
  const float* ew3 = (const float*)d_in[5];
  const float* eb3 = (const float*)d_in[6];
  const float* cb  = (const float*)d_in[7];
  const float* dw1 = (const float*)d_in[8];
  const float* db1 = (const float*)d_in[9];
  const float* dw2 = (const float*)d_in[10];
  const float* db2 = (const float*)d_in[11];
  const float* dw3 = (const float*)d_in[12];
  const float* db3 = (const float*)d_in[13];
  float* out = (float*)d_out;

  char* ws = (char*)d_ws;
  float* acc = (float*)ws;                         // acc[0]=recon ss, acc[1]=vq ss
  unsigned short* zeropg = (unsigned short*)(ws + 256);  // 512B zero page
  char* p = ws + 1024;
  unsigned short* wb2  = (unsigned short*)p; p += 524288;   // conv2  16*8*4*512*2
  unsigned short* wb3  = (unsigned short*)p; p += 147456;   // conv3   9*8*2*512*2
  unsigned short* wb4  = (unsigned short*)p; p += 73728;    // conv4   9*8*1*512*2
  unsigned short* wbd1 = (unsigned short*)p; p += 262144;   // dc1  16*4*4*512*2
  unsigned short* wbd2 = (unsigned short*)p; p += 524288;   // dc2  16*8*4*512*2
  size_t fixed = (size_t)(p - ws);

  // per-image NHWC scratch: h1/d1 1MB + h2 256KB + ze 256KB + zq 128KB + d2 4MB
  const size_t PER_IMG = 5898240ull;
  int C = 64;
  while (C > 1 && fixed + PER_IMG * (size_t)C > ws_size) C >>= 1;

  unsigned short* h1 = (unsigned short*)p; p += (size_t)C * 1048576ull;
  unsigned short* h2 = (unsigned short*)p; p += (size_t)C * 262144ull;
  float*          ze = (float*)p;          p += (size_t)C * 262144ull;
  unsigned short* zq = (unsigned short*)p; p += (size_t)C * 131072ull;
  unsigned short* d2 = (unsigned short*)p;

  hipMemsetAsync(ws, 0, 1024, stream);   // loss accumulators + zero page
  repack_conv_w<128, 16, 4><<<(16 * 8 * 4 * 512 + 255) / 256, 256, 0, stream>>>(ew2, wb2, 128);
  repack_conv_w<128, 9, 2><<<(9 * 8 * 2 * 512 + 255) / 256, 256, 0, stream>>>(ew3, wb3, 64);
  repack_conv_w<128, 9, 1><<<(9 * 8 * 1 * 512 + 255) / 256, 256, 0, stream>>>(dw3, wb4, 3);
  repack_deconv_w<64, 128, 4><<<(16 * 4 * 4 * 512 + 255) / 256, 256, 0, stream>>>(dw1, wbd1);
  repack_deconv_w<128, 128, 4><<<(16 * 8 * 4 * 512 + 255) / 256, 256, 0, stream>>>(dw2, wbd2);

  for (int n0 = 0; n0 < 64; n0 += C) {
    const float* xc = x + (size_t)n0 * 49152;
    float* oc = out + (size_t)n0 * 49152;
    conv1_k<<<C * 512, 256, 0, stream>>>(xc, ew1, eb1, h1);
    mconv_k<128, 128, 4, 64, 64, 32, 32, 16, 4, 2, false, true, false>
        <<<C * 8, 256, 0, stream>>>(h1, wb2, eb2, h2, zeropg);
    mconv_k<128, 64, 2, 32, 32, 32, 32, 9, 3, 1, false, false, true>
        <<<C * 8, 256, 0, stream>>>(h2, wb3, eb3, ze, zeropg);
    vq_k<<<C * 4, 256, 0, stream>>>(ze, cb, zq, acc + 1);
    mconv_k<64, 128, 4, 32, 32, 32, 32, 4, 2, 1, true, true, false>
        <<<dim3(C * 8, 4), 256, 0, stream>>>(zq, wbd1, db1, h1, zeropg);
    mconv_k<128, 128, 4, 64, 64, 64, 64, 4, 2, 1, true, true, false>
        <<<dim3(C * 32, 4), 256, 0, stream>>>(h1, wbd2, db2, d2, zeropg);
    conv4_k<<<C * 128, 256, 0, stream>>>(d2, wb4, db3, xc, oc, acc, zeropg);
  }
  finalize_k<<<1, 64, 0, stream>>>(acc, out);
}

// Round 4
// 1548.259 us; speedup vs baseline: 9.4878x; 1.4010x over previous
//
#include <hip/hip_runtime.h>
#include <hip/hip_bf16.h>

// ---- VQ-VAE forward, round 4 ----------------------------------------------
// r3 -> r4 changes (profile: vq_k 281us top, 1-block/CU + LDS conflicts;
// mconv L2-load-bound at 1.25 16B-loads/MFMA):
//  1. VQ via MFMA: dist = cnorm - 2*z.c^T, in-register argmin, butterfly min.
//  2. mconv: M=64/wave (2 A-frags per B-frag) -> 0.75 loads/MFMA.
//  3. conv4 on 16x16x32 MFMA (N=16 pad, half the padded FLOPs of N=32).
// Layouts (HW-verified per guide):
//  32x32x16_bf16: A[m=lane&31][k=(lane>>5)*8+j], B[k][n=lane&31],
//                 D: col=lane&31, row=(reg&3)+8*(reg>>2)+4*(lane>>5).
//  16x16x32_bf16: A[m=lane&15][k=(lane>>4)*8+j], B[k][n=lane&15],
//                 D: col=lane&15, row=(lane>>4)*4+reg.
// Deconv k4s2p1 parity (a,b): out(2q+a,2r+b) += in(q+a-i, r+b-j)*
//   w[ci][co][2i+1-a][2j+1-b] (verified r2/r3).

typedef __attribute__((ext_vector_type(8))) short short8;
typedef __attribute__((ext_vector_type(16))) float f32x16;
typedef __attribute__((ext_vector_type(4))) float f32x4;

__device__ __forceinline__ unsigned short f2bf(float f) {
  union { __hip_bfloat16 b; unsigned short u; } cv;
  cv.b = __float2bfloat16(f);
  return cv.u;
}
__device__ __forceinline__ unsigned pack2bf(float a, float b) {
  return (unsigned)f2bf(a) | ((unsigned)f2bf(b) << 16);
}

// ---------------- weight repack: conv layers  w[CO][CI][NTAP] fp32 -> frags
template<int CI, int NTAP, int NT>
__global__ void repack_conv_w(const float* __restrict__ w,
                              unsigned short* __restrict__ wb, int co_real) {
  const int KC = CI / 16;
  const int total = NTAP * KC * NT * 512;
  int i = blockIdx.x * 256 + threadIdx.x;
  if (i >= total) return;
  int j = i & 7, lane = (i >> 3) & 63, t2 = i >> 9;
  int nt = t2 % NT; t2 /= NT;
  int kc = t2 % KC; int tap = t2 / KC;
  int co = nt * 32 + (lane & 31);
  int ci = kc * 16 + (lane >> 5) * 8 + j;
  float v = (co < co_real) ? w[(co * CI + ci) * NTAP + tap] : 0.f;
  wb[i] = f2bf(v);
}

// ---------------- weight repack: deconv  w[CI][CO][4][4] fp32 -> frags/class
template<int CI, int CO, int NT>
__global__ void repack_deconv_w(const float* __restrict__ w,
                                unsigned short* __restrict__ wb) {
  const int KC = CI / 16;
  const int total = 16 * KC * NT * 512;   // 4 cls * 4 taps
  int i = blockIdx.x * 256 + threadIdx.x;
  if (i >= total) return;
  int j = i & 7, lane = (i >> 3) & 63, t2 = i >> 9;
  int nt = t2 % NT; t2 /= NT;
  int kc = t2 % KC; t2 /= KC;
  int tap = t2 & 3, cls = t2 >> 2;
  int a = cls >> 1, b = cls & 1, ti = tap >> 1, tj = tap & 1;
  int kh = 2 * ti + 1 - a, kw = 2 * tj + 1 - b;
  int co = nt * 32 + (lane & 31);
  int ci = kc * 16 + (lane >> 5) * 8 + j;
  wb[i] = f2bf(w[((ci * CO + co) * 4 + kh) * 4 + kw]);
}

// ---------------- weight repack: conv4 16x16 frags  dw3[3][128][3][3]
__global__ void repack_conv4_w(const float* __restrict__ w,
                               unsigned short* __restrict__ wb) {
  const int total = 9 * 4 * 512;
  int i = blockIdx.x * 256 + threadIdx.x;
  if (i >= total) return;
  int j = i & 7, lane = (i >> 3) & 63, tk = i >> 9;
  int kc = tk & 3, t = tk >> 2;
  int co = lane & 15;
  int ci = kc * 32 + (lane >> 4) * 8 + j;
  float v = (co < 3) ? w[(co * 128 + ci) * 9 + t] : 0.f;
  wb[i] = f2bf(v);
}

// ---------------- codebook repack -> bf16 B-frags [tile16][kc4][lane64][8]
__global__ void repack_cb(const float* __restrict__ cb,
                          unsigned short* __restrict__ cbf) {
  int i = blockIdx.x * 256 + threadIdx.x;   // 32768
  int j = i & 7, lane = (i >> 3) & 63;
  int kc = (i >> 9) & 3, tile = i >> 11;
  int code = tile * 32 + (lane & 31);
  int d = kc * 16 + (lane >> 5) * 8 + j;
  cbf[i] = f2bf(cb[code * 64 + d]);
}
__global__ void cnorm_k(const float* __restrict__ cb, float* __restrict__ cn) {
  int k = blockIdx.x * 256 + threadIdx.x;
  if (k >= 512) return;
  const float4* r = (const float4*)(cb + k * 64);
  float s = 0.f;
  #pragma unroll
  for (int q = 0; q < 16; ++q) {
    float4 v = r[q];
    s = fmaf(v.x, v.x, s); s = fmaf(v.y, v.y, s);
    s = fmaf(v.z, v.z, s); s = fmaf(v.w, v.w, s);
  }
  cn[k] = s;
}

// ---------------- conv1: x NCHW fp32 [C,3,128,128] -> h1 NHWC bf16 [C,64,64,128]
__global__ __launch_bounds__(256) void conv1_k(
    const float* __restrict__ x, const float* __restrict__ w,
    const float* __restrict__ bias, unsigned short* __restrict__ out) {
  __shared__ float sw[48 * 128];   // [tap][co]
  __shared__ float sx[3 * 4 * 18]; // [ci][kh][col]
  int tid = threadIdx.x;
  int n = blockIdx.x >> 9, rr = blockIdx.x & 511;
  int oh = rr >> 3, ow0 = (rr & 7) * 8;
  for (int i = tid; i < 6144; i += 256) {
    int tap = i >> 7, co = i & 127;
    sw[i] = w[co * 48 + tap];
  }
  for (int i = tid; i < 216; i += 256) {
    int ci = i / 72, r = i % 72, kh = r / 18, c = r % 18;
    int ih = 2 * oh - 1 + kh, iw = 2 * ow0 - 1 + c;
    float v = 0.f;
    if ((unsigned)ih < 128u && (unsigned)iw < 128u)
      v = x[(n * 3 + ci) * 16384 + ih * 128 + iw];
    sx[i] = v;
  }
  __syncthreads();
  int p = tid >> 5, co0 = (tid & 31) * 4;
  float xv[48];
  #pragma unroll
  for (int ci = 0; ci < 3; ++ci)
    #pragma unroll
    for (int kh = 0; kh < 4; ++kh)
      #pragma unroll
      for (int kw = 0; kw < 4; ++kw)
        xv[ci * 16 + kh * 4 + kw] = sx[ci * 72 + kh * 18 + 2 * p + kw];
  float a0 = bias[co0], a1 = bias[co0 + 1], a2 = bias[co0 + 2], a3 = bias[co0 + 3];
  #pragma unroll
  for (int tap = 0; tap < 48; ++tap) {
    float4 w4 = *(const float4*)&sw[tap * 128 + co0];
    a0 = fmaf(xv[tap], w4.x, a0);
    a1 = fmaf(xv[tap], w4.y, a1);
    a2 = fmaf(xv[tap], w4.z, a2);
    a3 = fmaf(xv[tap], w4.w, a3);
  }
  a0 = fmaxf(a0, 0.f); a1 = fmaxf(a1, 0.f); a2 = fmaxf(a2, 0.f); a3 = fmaxf(a3, 0.f);
  uint2 u; u.x = pack2bf(a0, a1); u.y = pack2bf(a2, a3);
  *(uint2*)(out + ((n * 64 + oh) * 64 + ow0 + p) * 128 + co0) = u;
}

// ---------------- generic MFMA conv / parity-deconv, M=64 per wave
template<int CI, int CO, int NT, int IH, int IW, int OH, int OW, int NTAP,
         int KW, int STRIDE, bool DECONV, bool RELU, bool F32OUT>
__global__ __launch_bounds__(256, 2) void mconv_k(
    const unsigned short* __restrict__ in, const unsigned short* __restrict__ wb,
    const float* __restrict__ bias, void* __restrict__ outv,
    const unsigned short* __restrict__ zeropg) {
  const int KC = CI / 16;
  int lane = threadIdx.x & 63, wv = threadIdx.x >> 6;
  int m0 = blockIdx.x * 256 + wv * 64;
  int cls = DECONV ? blockIdx.y : 0;
  int ca = cls >> 1, cb2 = cls & 1;
  int khalf = lane >> 5;
  int n_[2], oh_[2], ow_[2];
  #pragma unroll
  for (int s = 0; s < 2; ++s) {
    int mm = m0 + s * 32 + (lane & 31);
    n_[s] = mm / (OH * OW);
    int rem = mm % (OH * OW);
    oh_[s] = rem / OW; ow_[s] = rem % OW;
  }
  f32x16 acc[2][NT];
  #pragma unroll
  for (int s = 0; s < 2; ++s)
    #pragma unroll
    for (int t = 0; t < NT; ++t)
      #pragma unroll
      for (int e = 0; e < 16; ++e) acc[s][t][e] = 0.f;
  const unsigned short* wbc = wb + cls * (NTAP * KC * NT * 512);
  #pragma unroll
  for (int t = 0; t < NTAP; ++t) {
    const unsigned short* ap[2];
    #pragma unroll
    for (int s = 0; s < 2; ++s) {
      int ih, iw;
      if (DECONV) { ih = oh_[s] + ca - (t >> 1); iw = ow_[s] + cb2 - (t & 1); }
      else        { ih = STRIDE * oh_[s] - 1 + t / KW; iw = STRIDE * ow_[s] - 1 + t % KW; }
      bool valid = ((unsigned)ih < (unsigned)IH) && ((unsigned)iw < (unsigned)IW);
      ap[s] = valid ? (in + ((n_[s] * IH + ih) * IW + iw) * CI + khalf * 8)
                    : (zeropg + khalf * 8);
    }
    const unsigned short* bp = wbc + t * (KC * NT * 512) + lane * 8;
    #pragma unroll
    for (int kc = 0; kc < KC; ++kc) {
      short8 a0 = *(const short8*)(ap[0] + kc * 16);
      short8 a1 = *(const short8*)(ap[1] + kc * 16);
      #pragma unroll
      for (int nt = 0; nt < NT; ++nt) {
        short8 bf_ = *(const short8*)(bp + (kc * NT + nt) * 512);
        acc[0][nt] = __builtin_amdgcn_mfma_f32_32x32x16_bf16(a0, bf_, acc[0][nt], 0, 0, 0);
        acc[1][nt] = __builtin_amdgcn_mfma_f32_32x32x16_bf16(a1, bf_, acc[1][nt], 0, 0, 0);
      }
    }
  }
  int col = lane & 31;
  #pragma unroll
  for (int s = 0; s < 2; ++s)
    #pragma unroll
    for (int nt = 0; nt < NT; ++nt) {
      int co = nt * 32 + col;
      float bv = bias[co];
      #pragma unroll
      for (int r = 0; r < 16; ++r) {
        int mrow = (r & 3) + 8 * (r >> 2) + 4 * khalf;
        int mp = m0 + s * 32 + mrow;
        int n2 = mp / (OH * OW), r2 = mp % (OH * OW);
        int oh2 = r2 / OW, ow2 = r2 % OW;
        float v = acc[s][nt][r] + bv;
        if (RELU) v = fmaxf(v, 0.f);
        int idx;
        if (DECONV)
          idx = ((n2 * (2 * OH) + 2 * oh2 + ca) * (2 * OW) + 2 * ow2 + cb2) * CO + co;
        else
          idx = ((n2 * OH + oh2) * OW + ow2) * CO + co;
        if (F32OUT) ((float*)outv)[idx] = v;
        else        ((unsigned short*)outv)[idx] = f2bf(v);
      }
    }
}

// ---------------- VQ via MFMA: ze fp32 [P,64] -> zq bf16 [P,64], vq ss
__global__ __launch_bounds__(256) void vq2_k(
    const float* __restrict__ ze, const float* __restrict__ cb,
    const unsigned short* __restrict__ cbf, const float* __restrict__ cnorm,
    unsigned short* __restrict__ zq, float* __restrict__ acc_loss) {
  __shared__ int s_idx[4][32];
  int lane = threadIdx.x & 63, wv = threadIdx.x >> 6;
  int m0 = blockIdx.x * 128 + wv * 32;
  int col = lane & 31, khalf = lane >> 5;
  const float* zrow = ze + (size_t)(m0 + col) * 64 + khalf * 8;
  short8 af[4];
  #pragma unroll
  for (int kc = 0; kc < 4; ++kc) {
    float4 a = *(const float4*)(zrow + kc * 16);
    float4 b = *(const float4*)(zrow + kc * 16 + 4);
    short8 f;
    f[0] = (short)f2bf(a.x); f[1] = (short)f2bf(a.y);
    f[2] = (short)f2bf(a.z); f[3] = (short)f2bf(a.w);
    f[4] = (short)f2bf(b.x); f[5] = (short)f2bf(b.y);
    f[6] = (short)f2bf(b.z); f[7] = (short)f2bf(b.w);
    af[kc] = f;
  }
  float best[16]; int bidx[16];
  #pragma unroll
  for (int r = 0; r < 16; ++r) { best[r] = 3.4e38f; bidx[r] = 0; }
  #pragma unroll
  for (int tt = 0; tt < 16; ++tt) {
    f32x16 acc;
    #pragma unroll
    for (int e = 0; e < 16; ++e) acc[e] = 0.f;
    #pragma unroll
    for (int kc = 0; kc < 4; ++kc) {
      short8 bf_ = *(const short8*)(cbf + ((tt * 4 + kc) * 64 + lane) * 8);
      acc = __builtin_amdgcn_mfma_f32_32x32x16_bf16(af[kc], bf_, acc, 0, 0, 0);
    }
    float cn = cnorm[tt * 32 + col];
    int code = tt * 32 + col;
    #pragma unroll
    for (int r = 0; r < 16; ++r) {
      float d = fmaf(-2.f, acc[r], cn);
      if (d < best[r]) { best[r] = d; bidx[r] = code; }
    }
  }
  #pragma unroll
  for (int off = 1; off < 32; off <<= 1) {
    #pragma unroll
    for (int r = 0; r < 16; ++r) {
      float ob = __shfl_xor(best[r], off, 64);
      int   oi = __shfl_xor(bidx[r], off, 64);
      if (ob < best[r]) { best[r] = ob; bidx[r] = oi; }
    }
  }
  if (col == 0) {
    #pragma unroll
    for (int r = 0; r < 16; ++r)
      s_idx[wv][(r & 3) + 8 * (r >> 2) + 4 * khalf] = bidx[r];
  }
  __syncthreads();
  int row = lane >> 1, half = lane & 1;
  int m = m0 + row;
  int idx = s_idx[wv][row];
  const float4* crow = (const float4*)(cb + idx * 64 + half * 32);
  const float4* zp = (const float4*)(ze + (size_t)m * 64 + half * 32);
  uint2* zqp = (uint2*)(zq + (size_t)m * 64 + half * 32);
  float lsum = 0.f;
  #pragma unroll
  for (int q = 0; q < 8; ++q) {
    float4 c4 = crow[q];
    float4 z4 = zp[q];
    uint2 u; u.x = pack2bf(c4.x, c4.y); u.y = pack2bf(c4.z, c4.w);
    zqp[q] = u;
    float d;
    d = z4.x - c4.x; lsum = fmaf(d, d, lsum);
    d = z4.y - c4.y; lsum = fmaf(d, d, lsum);
    d = z4.z - c4.z; lsum = fmaf(d, d, lsum);
    d = z4.w - c4.w; lsum = fmaf(d, d, lsum);
  }
  #pragma unroll
  for (int off = 32; off > 0; off >>= 1) lsum += __shfl_down(lsum, off, 64);
  if (lane == 0) atomicAdd(acc_loss, lsum);
}

// ---------------- conv4: d2 NHWC bf16 -> x_recon NCHW fp32 (+recon loss)
// 16x16x32 MFMA, N=16 (co pad 3->16), M=64/wave via 4 sub-tiles.
__global__ __launch_bounds__(256) void conv4_k(
    const unsigned short* __restrict__ in, const unsigned short* __restrict__ wb,
    const float* __restrict__ bias, const float* __restrict__ x,
    float* __restrict__ out, float* __restrict__ acc_loss,
    const unsigned short* __restrict__ zeropg) {
  int lane = threadIdx.x & 63, wv = threadIdx.x >> 6;
  int m0 = blockIdx.x * 256 + wv * 64;
  int quad = lane >> 4, mloc = lane & 15;
  int n_[4], oh_[4], ow_[4];
  #pragma unroll
  for (int s = 0; s < 4; ++s) {
    int mm = m0 + s * 16 + mloc;
    n_[s] = mm >> 14;
    int rem = mm & 16383;
    oh_[s] = rem >> 7; ow_[s] = rem & 127;
  }
  f32x4 acc[4];
  #pragma unroll
  for (int s = 0; s < 4; ++s)
    #pragma unroll
    for (int e = 0; e < 4; ++e) acc[s][e] = 0.f;
  #pragma unroll
  for (int t = 0; t < 9; ++t) {
    int dh = t / 3 - 1, dw = t % 3 - 1;
    const unsigned short* ap[4];
    #pragma unroll
    for (int s = 0; s < 4; ++s) {
      int ih = oh_[s] + dh, iw = ow_[s] + dw;
      bool valid = ((unsigned)ih < 128u) && ((unsigned)iw < 128u);
      ap[s] = valid ? (in + ((n_[s] * 128 + ih) * 128 + iw) * 128 + quad * 8)
                    : (zeropg + quad * 8);
    }
    const unsigned short* bp = wb + t * 4 * 512 + lane * 8;
    #pragma unroll
    for (int kc = 0; kc < 4; ++kc) {
      short8 bf_ = *(const short8*)(bp + kc * 512);
      #pragma unroll
      for (int s = 0; s < 4; ++s) {
        short8 a = *(const short8*)(ap[s] + kc * 32);
        acc[s] = __builtin_amdgcn_mfma_f32_16x16x32_bf16(a, bf_, acc[s], 0, 0, 0);
      }
    }
  }
  int co = lane & 15;
  float bv = (co < 3) ? bias[co] : 0.f;
  float lsum = 0.f;
  #pragma unroll
  for (int s = 0; s < 4; ++s)
    #pragma unroll
    for (int r = 0; r < 4; ++r) {
      int m = m0 + s * 16 + quad * 4 + r;
      if (co < 3) {
        float v = acc[s][r] + bv;
        int n2 = m >> 14, r2 = m & 16383;
        int gi = (n2 * 3 + co) * 16384 + r2;
        out[gi] = v;
        float d = v - x[gi];
        lsum = fmaf(d, d, lsum);
      }
    }
  #pragma unroll
  for (int off = 32; off > 0; off >>= 1) lsum += __shfl_down(lsum, off, 64);
  if (lane == 0) atomicAdd(acc_loss, lsum);
}

// ---------------- finalize losses
__global__ void finalize_k(const float* __restrict__ accv, float* __restrict__ out) {
  if (threadIdx.x == 0 && blockIdx.x == 0) {
    float recon = accv[0] / 3145728.0f;
    float vq = 1.25f * accv[1] / 4194304.0f;
    out[3145728] = recon + vq;
    out[3145729] = recon;
    out[3145730] = vq;
  }
}

extern "C" void kernel_launch(void* const* d_in, const int* in_sizes, int n_in,
                              void* d_out, int out_size, void* d_ws, size_t ws_size,
                              hipStream_t stream) {
  const float* x   = (const float*)d_in[0];
  const float* ew1 = (const float*)d_in[1];
  const float* eb1 = (const float*)d_in[2];
  const float* ew2 = (const float*)d_in[3];
  const float* eb2 = (const float*)d_in[4];
  const float* ew3 = (const float*)d_in[5];
  const float* eb3 = (const float*)d_in[6];
  const float* cb  = (const float*)d_in[7];
  const float* dw1 = (const float*)d_in[8];
  const float* db1 = (const float*)d_in[9];
  const float* dw2 = (const float*)d_in[10];
  const float* db2 = (const float*)d_in[11];
  const float* dw3 = (const float*)d_in[12];
  const float* db3 = (const float*)d_in[13];
  float* out = (float*)d_out;

  char* ws = (char*)d_ws;
  float* acc = (float*)ws;                               // [0]=recon ss, [1]=vq ss
  unsigned short* zeropg = (unsigned short*)(ws + 256);  // 512B zero page
  char* p = ws + 1024;
  unsigned short* wb2  = (unsigned short*)p; p += 524288;  // conv2 16*8*4*512*2
  unsigned short* wb3  = (unsigned short*)p; p += 147456;  // conv3  9*8*2*512*2
  unsigned short* wb4  = (unsigned short*)p; p += 36864;   // conv4 16x16: 9*4*512*2
  unsigned short* wbd1 = (unsigned short*)p; p += 262144;  // dc1 16*4*4*512*2
  unsigned short* wbd2 = (unsigned short*)p; p += 524288;  // dc2 16*8*4*512*2
  unsigned short* cbf  = (unsigned short*)p; p += 65536;   // cb frags 16*4*64*8*2
  float*          cnrm = (float*)p;          p += 2048;
  size_t fixed = (size_t)(p - ws);

  const size_t PER_IMG = 5898240ull;   // h1 1MB + h2 256K + ze 256K + zq 128K + d2 4MB
  int C = 64;
  while (C > 1 && fixed + PER_IMG * (size_t)C > ws_size) C >>= 1;

  unsigned short* h1 = (unsigned short*)p; p += (size_t)C * 1048576ull;
  unsigned short* h2 = (unsigned short*)p; p += (size_t)C * 262144ull;
  float*          ze = (float*)p;          p += (size_t)C * 262144ull;
  unsigned short* zq = (unsigned short*)p; p += (size_t)C * 131072ull;
  unsigned short* d2 = (unsigned short*)p;

  hipMemsetAsync(ws, 0, 1024, stream);   // loss accumulators + zero page
  repack_conv_w<128, 16, 4><<<(16 * 8 * 4 * 512 + 255) / 256, 256, 0, stream>>>(ew2, wb2, 128);
  repack_conv_w<128, 9, 2><<<(9 * 8 * 2 * 512 + 255) / 256, 256, 0, stream>>>(ew3, wb3, 64);
  repack_conv4_w<<<(9 * 4 * 512 + 255) / 256, 256, 0, stream>>>(dw3, wb4);
  repack_deconv_w<64, 128, 4><<<(16 * 4 * 4 * 512 + 255) / 256, 256, 0, stream>>>(dw1, wbd1);
  repack_deconv_w<128, 128, 4><<<(16 * 8 * 4 * 512 + 255) / 256, 256, 0, stream>>>(dw2, wbd2);
  repack_cb<<<128, 256, 0, stream>>>(cb, cbf);
  cnorm_k<<<2, 256, 0, stream>>>(cb, cnrm);

  for (int n0 = 0; n0 < 64; n0 += C) {
    const float* xc = x + (size_t)n0 * 49152;
    float* oc = out + (size_t)n0 * 49152;
    conv1_k<<<C * 512, 256, 0, stream>>>(xc, ew1, eb1, h1);
    mconv_k<128, 128, 4, 64, 64, 32, 32, 16, 4, 2, false, true, false>
        <<<C * 4, 256, 0, stream>>>(h1, wb2, eb2, h2, zeropg);
    mconv_k<128, 64, 2, 32, 32, 32, 32, 9, 3, 1, false, false, true>
        <<<C * 4, 256, 0, stream>>>(h2, wb3, eb3, ze, zeropg);
    vq2_k<<<C * 8, 256, 0, stream>>>(ze, cb, cbf, cnrm, zq, acc + 1);
    mconv_k<64, 128, 4, 32, 32, 32, 32, 4, 2, 1, true, true, false>
        <<<dim3(C * 4, 4), 256, 0, stream>>>(zq, wbd1, db1, h1, zeropg);
    mconv_k<128, 128, 4, 64, 64, 64, 64, 4, 2, 1, true, true, false>
        <<<dim3(C * 16, 4), 256, 0, stream>>>(h1, wbd2, db2, d2, zeropg);
    conv4_k<<<C * 64, 256, 0, stream>>>(d2, wb4, db3, xc, oc, acc, zeropg);
  }
  finalize_k<<<1, 64, 0, stream>>>(acc, out);
}

// Round 5
// 1381.776 us; speedup vs baseline: 10.6310x; 1.1205x over previous
//
#include <hip/hip_runtime.h>
#include <hip/hip_bf16.h>

// ---- VQ-VAE forward, round 5 ----------------------------------------------
// r4 diagnosis: mconv latency-bound (MfmaUtil 14%, VALUBusy 10%, Occ 22%) --
// all operands from L2 (~200cyc). r5: B-frags in LDS (double-buffered per
// tap, prefetched via regs), M=128/wave (S=4) so B-bytes/MFMA=256B fits the
// 128 B/cyc LDS port; NT=2 with co-groups on grid.z. Full-batch encoder
// (scratch 109MB) + chunked decoder (d2 = CD*4MB). conv4 B and vq codebook
// staged in LDS.
// Layouts (HW-verified): 32x32x16_bf16 A[m=lane&31][k=(lane>>5)*8+j],
//   D: col=lane&31, row=(reg&3)+8*(reg>>2)+4*(lane>>5).
// 16x16x32_bf16 A[m=lane&15][k=(lane>>4)*8+j], D: col=lane&15,
//   row=(lane>>4)*4+reg.
// Deconv k4s2p1 parity (a,b): out(2q+a,2r+b) += in(q+a-i, r+b-j)*
//   w[ci][co][2i+1-a][2j+1-b]  (verified r2-r4).

typedef __attribute__((ext_vector_type(8))) short short8;
typedef __attribute__((ext_vector_type(16))) float f32x16;
typedef __attribute__((ext_vector_type(4))) float f32x4;

__device__ __forceinline__ unsigned short f2bf(float f) {
  union { __hip_bfloat16 b; unsigned short u; } cv;
  cv.b = __float2bfloat16(f);
  return cv.u;
}
__device__ __forceinline__ unsigned pack2bf(float a, float b) {
  return (unsigned)f2bf(a) | ((unsigned)f2bf(b) << 16);
}

// ---------------- weight repack: conv layers  w[CO][CI][NTAP] fp32 -> frags
// layout: [tap][kc][ntall][lane][8]
template<int CI, int NTAP, int NTALL>
__global__ void repack_conv_w(const float* __restrict__ w,
                              unsigned short* __restrict__ wb, int co_real) {
  const int KC = CI / 16;
  const int total = NTAP * KC * NTALL * 512;
  int i = blockIdx.x * 256 + threadIdx.x;
  if (i >= total) return;
  int j = i & 7, lane = (i >> 3) & 63, t2 = i >> 9;
  int nt = t2 % NTALL; t2 /= NTALL;
  int kc = t2 % KC; int tap = t2 / KC;
  int co = nt * 32 + (lane & 31);
  int ci = kc * 16 + (lane >> 5) * 8 + j;
  float v = (co < co_real) ? w[(co * CI + ci) * NTAP + tap] : 0.f;
  wb[i] = f2bf(v);
}

// ---------------- weight repack: deconv  w[CI][CO][4][4] fp32 -> frags/class
// layout: [cls][tap][kc][ntall][lane][8]
template<int CI, int CO, int NTALL>
__global__ void repack_deconv_w(const float* __restrict__ w,
                                unsigned short* __restrict__ wb) {
  const int KC = CI / 16;
  const int total = 16 * KC * NTALL * 512;
  int i = blockIdx.x * 256 + threadIdx.x;
  if (i >= total) return;
  int j = i & 7, lane = (i >> 3) & 63, t2 = i >> 9;
  int nt = t2 % NTALL; t2 /= NTALL;
  int kc = t2 % KC; t2 /= KC;
  int tap = t2 & 3, cls = t2 >> 2;
  int a = cls >> 1, b = cls & 1, ti = tap >> 1, tj = tap & 1;
  int kh = 2 * ti + 1 - a, kw = 2 * tj + 1 - b;
  int co = nt * 32 + (lane & 31);
  int ci = kc * 16 + (lane >> 5) * 8 + j;
  wb[i] = f2bf(w[((ci * CO + co) * 4 + kh) * 4 + kw]);
}

// ---------------- weight repack: conv4 16x16 frags  dw3[3][128][3][3]
__global__ void repack_conv4_w(const float* __restrict__ w,
                               unsigned short* __restrict__ wb) {
  const int total = 9 * 4 * 512;
  int i = blockIdx.x * 256 + threadIdx.x;
  if (i >= total) return;
  int j = i & 7, lane = (i >> 3) & 63, tk = i >> 9;
  int kc = tk & 3, t = tk >> 2;
  int co = lane & 15;
  int ci = kc * 32 + (lane >> 4) * 8 + j;
  float v = (co < 3) ? w[(co * 128 + ci) * 9 + t] : 0.f;
  wb[i] = f2bf(v);
}

// ---------------- codebook repack -> bf16 B-frags [tile16][kc4][lane64][8]
__global__ void repack_cb(const float* __restrict__ cb,
                          unsigned short* __restrict__ cbf) {
  int i = blockIdx.x * 256 + threadIdx.x;   // 32768
  int j = i & 7, lane = (i >> 3) & 63;
  int kc = (i >> 9) & 3, tile = i >> 11;
  int code = tile * 32 + (lane & 31);
  int d = kc * 16 + (lane >> 5) * 8 + j;
  cbf[i] = f2bf(cb[code * 64 + d]);
}
__global__ void cnorm_k(const float* __restrict__ cb, float* __restrict__ cn) {
  int k = blockIdx.x * 256 + threadIdx.x;
  if (k >= 512) return;
  const float4* r = (const float4*)(cb + k * 64);
  float s = 0.f;
  #pragma unroll
  for (int q = 0; q < 16; ++q) {
    float4 v = r[q];
    s = fmaf(v.x, v.x, s); s = fmaf(v.y, v.y, s);
    s = fmaf(v.z, v.z, s); s = fmaf(v.w, v.w, s);
  }
  cn[k] = s;
}

// ---------------- conv1: x NCHW fp32 [64,3,128,128] -> h1 NHWC bf16
__global__ __launch_bounds__(256) void conv1_k(
    const float* __restrict__ x, const float* __restrict__ w,
    const float* __restrict__ bias, unsigned short* __restrict__ out) {
  __shared__ float sw[48 * 128];   // [tap][co]
  __shared__ float sx[3 * 4 * 18]; // [ci][kh][col]
  int tid = threadIdx.x;
  int n = blockIdx.x >> 9, rr = blockIdx.x & 511;
  int oh = rr >> 3, ow0 = (rr & 7) * 8;
  for (int i = tid; i < 6144; i += 256) {
    int tap = i >> 7, co = i & 127;
    sw[i] = w[co * 48 + tap];
  }
  for (int i = tid; i < 216; i += 256) {
    int ci = i / 72, r = i % 72, kh = r / 18, c = r % 18;
    int ih = 2 * oh - 1 + kh, iw = 2 * ow0 - 1 + c;
    float v = 0.f;
    if ((unsigned)ih < 128u && (unsigned)iw < 128u)
      v = x[(n * 3 + ci) * 16384 + ih * 128 + iw];
    sx[i] = v;
  }
  __syncthreads();
  int p = tid >> 5, co0 = (tid & 31) * 4;
  float xv[48];
  #pragma unroll
  for (int ci = 0; ci < 3; ++ci)
    #pragma unroll
    for (int kh = 0; kh < 4; ++kh)
      #pragma unroll
      for (int kw = 0; kw < 4; ++kw)
        xv[ci * 16 + kh * 4 + kw] = sx[ci * 72 + kh * 18 + 2 * p + kw];
  float a0 = bias[co0], a1 = bias[co0 + 1], a2 = bias[co0 + 2], a3 = bias[co0 + 3];
  #pragma unroll
  for (int tap = 0; tap < 48; ++tap) {
    float4 w4 = *(const float4*)&sw[tap * 128 + co0];
    a0 = fmaf(xv[tap], w4.x, a0);
    a1 = fmaf(xv[tap], w4.y, a1);
    a2 = fmaf(xv[tap], w4.z, a2);
    a3 = fmaf(xv[tap], w4.w, a3);
  }
  a0 = fmaxf(a0, 0.f); a1 = fmaxf(a1, 0.f); a2 = fmaxf(a2, 0.f); a3 = fmaxf(a3, 0.f);
  uint2 u; u.x = pack2bf(a0, a1); u.y = pack2bf(a2, a3);
  *(uint2*)(out + ((n * 64 + oh) * 64 + ow0 + p) * 128 + co0) = u;
}

// ---------------- generic MFMA conv / parity-deconv
// M = 32*S per wave, N = 32*NT per wave (co-group = blockIdx.z).
// B-frags double-buffered in LDS per tap, prefetched via registers.
template<int CI, int CO, int NTALL, int NT, int S, int IH, int IW, int OH, int OW,
         int NTAP, int KW, int STRIDE, bool DECONV, bool RELU, bool F32OUT>
__global__ __launch_bounds__(256, 2) void mconv_k(
    const unsigned short* __restrict__ in, const unsigned short* __restrict__ wb,
    const float* __restrict__ bias, void* __restrict__ outv,
    const unsigned short* __restrict__ zeropg) {
  const int KC = CI / 16;
  const int TSZ = KC * NT * 512;       // shorts per staged tap slice
  const int STG = KC * NT / 4;         // uint4 per thread per stage
  __shared__ unsigned short sB[2][TSZ];
  int tid = threadIdx.x, lane = tid & 63, wv = tid >> 6;
  int m0 = blockIdx.x * (128 * S) + wv * (32 * S);
  int cls = DECONV ? blockIdx.y : 0;
  int cog = blockIdx.z;
  int ca = cls >> 1, cb2 = cls & 1;
  int khalf = lane >> 5;
  int n_[S], oh_[S], ow_[S];
  #pragma unroll
  for (int s = 0; s < S; ++s) {
    int mm = m0 + s * 32 + (lane & 31);
    n_[s] = mm / (OH * OW);
    int rem = mm % (OH * OW);
    oh_[s] = rem / OW; ow_[s] = rem % OW;
  }
  f32x16 acc[S][NT];
  #pragma unroll
  for (int s = 0; s < S; ++s)
    #pragma unroll
    for (int t = 0; t < NT; ++t)
      #pragma unroll
      for (int e = 0; e < 16; ++e) acc[s][t][e] = 0.f;

  const unsigned short* wcls = wb + (size_t)cls * NTAP * KC * NTALL * 512;
  uint4 st[STG];
  // prologue: stage tap 0 into buf 0
  #pragma unroll
  for (int q = 0; q < STG; ++q) {
    int i = q * 256 + tid;
    int kc = i / (NT * 64), r = i - kc * (NT * 64);
    st[q] = *(const uint4*)(wcls + (size_t)(kc * NTALL + cog * NT) * 512 + r * 8);
  }
  #pragma unroll
  for (int q = 0; q < STG; ++q) {
    int i = q * 256 + tid;
    *(uint4*)&sB[0][i * 8] = st[q];
  }
  __syncthreads();

  for (int t = 0; t < NTAP; ++t) {
    int cur = t & 1;
    if (t + 1 < NTAP) {
      const unsigned short* wt = wcls + (size_t)(t + 1) * KC * NTALL * 512;
      #pragma unroll
      for (int q = 0; q < STG; ++q) {
        int i = q * 256 + tid;
        int kc = i / (NT * 64), r = i - kc * (NT * 64);
        st[q] = *(const uint4*)(wt + (size_t)(kc * NTALL + cog * NT) * 512 + r * 8);
      }
    }
    // A pointers for this tap
    const unsigned short* ap[S];
    #pragma unroll
    for (int s = 0; s < S; ++s) {
      int ih, iw;
      if (DECONV) { ih = oh_[s] + ca - (t >> 1); iw = ow_[s] + cb2 - (t & 1); }
      else        { ih = STRIDE * oh_[s] - 1 + t / KW; iw = STRIDE * ow_[s] - 1 + t % KW; }
      bool valid = ((unsigned)ih < (unsigned)IH) && ((unsigned)iw < (unsigned)IW);
      ap[s] = valid ? (in + ((size_t)(n_[s] * IH + ih) * IW + iw) * CI + khalf * 8)
                    : (zeropg + khalf * 8);
    }
    #pragma unroll
    for (int kc = 0; kc < KC; ++kc) {
      short8 a[S];
      #pragma unroll
      for (int s = 0; s < S; ++s) a[s] = *(const short8*)(ap[s] + kc * 16);
      #pragma unroll
      for (int nt = 0; nt < NT; ++nt) {
        short8 b = *(const short8*)&sB[cur][(kc * NT + nt) * 512 + lane * 8];
        #pragma unroll
        for (int s = 0; s < S; ++s)
          acc[s][nt] = __builtin_amdgcn_mfma_f32_32x32x16_bf16(a[s], b, acc[s][nt], 0, 0, 0);
      }
    }
    if (t + 1 < NTAP) {
      #pragma unroll
      for (int q = 0; q < STG; ++q) {
        int i = q * 256 + tid;
        *(uint4*)&sB[cur ^ 1][i * 8] = st[q];
      }
    }
    __syncthreads();
  }

  int col = lane & 31;
  #pragma unroll
  for (int s = 0; s < S; ++s)
    #pragma unroll
    for (int nt = 0; nt < NT; ++nt) {
      int co = (cog * NT + nt) * 32 + col;
      float bv = bias[co];
      #pragma unroll
      for (int r = 0; r < 16; ++r) {
        int mrow = (r & 3) + 8 * (r >> 2) + 4 * khalf;
        int mp = m0 + s * 32 + mrow;
        int n2 = mp / (OH * OW), r2 = mp % (OH * OW);
        int oh2 = r2 / OW, ow2 = r2 % OW;
        float v = acc[s][nt][r] + bv;
        if (RELU) v = fmaxf(v, 0.f);
        size_t idx;
        if (DECONV)
          idx = ((size_t)(n2 * (2 * OH) + 2 * oh2 + ca) * (2 * OW) + 2 * ow2 + cb2) * CO + co;
        else
          idx = ((size_t)(n2 * OH + oh2) * OW + ow2) * CO + co;
        if (F32OUT) ((float*)outv)[idx] = v;
        else        ((unsigned short*)outv)[idx] = f2bf(v);
      }
    }
}

// ---------------- VQ via MFMA, codebook frags staged in LDS (2 phases x 32KB)
__global__ __launch_bounds__(256, 2) void vq2_k(
    const float* __restrict__ ze, const float* __restrict__ cb,
    const unsigned short* __restrict__ cbf, const float* __restrict__ cnorm,
    unsigned short* __restrict__ zq, float* __restrict__ acc_loss) {
  __shared__ unsigned short sC[16384];   // 8 tiles of B-frags (32 KB)
  __shared__ int s_idx[4][32];
  int tid = threadIdx.x, lane = tid & 63, wv = tid >> 6;
  int m0 = blockIdx.x * 128 + wv * 32;
  int col = lane & 31, khalf = lane >> 5;
  const float* zrow = ze + (size_t)(m0 + col) * 64 + khalf * 8;
  short8 af[4];
  #pragma unroll
  for (int kc = 0; kc < 4; ++kc) {
    float4 a = *(const float4*)(zrow + kc * 16);
    float4 b = *(const float4*)(zrow + kc * 16 + 4);
    short8 f;
    f[0] = (short)f2bf(a.x); f[1] = (short)f2bf(a.y);
    f[2] = (short)f2bf(a.z); f[3] = (short)f2bf(a.w);
    f[4] = (short)f2bf(b.x); f[5] = (short)f2bf(b.y);
    f[6] = (short)f2bf(b.z); f[7] = (short)f2bf(b.w);
    af[kc] = f;
  }
  float best[16]; int bidx[16];
  #pragma unroll
  for (int r = 0; r < 16; ++r) { best[r] = 3.4e38f; bidx[r] = 0; }
  for (int half = 0; half < 2; ++half) {
    #pragma unroll
    for (int q = 0; q < 8; ++q) {
      int i = q * 256 + tid;
      *(uint4*)&sC[i * 8] = *(const uint4*)(cbf + half * 16384 + i * 8);
    }
    __syncthreads();
    #pragma unroll
    for (int t8 = 0; t8 < 8; ++t8) {
      int tt = half * 8 + t8;
      f32x16 acc;
      #pragma unroll
      for (int e = 0; e < 16; ++e) acc[e] = 0.f;
      #pragma unroll
      for (int kc = 0; kc < 4; ++kc) {
        short8 bf_ = *(const short8*)&sC[(t8 * 4 + kc) * 512 + lane * 8];
        acc = __builtin_amdgcn_mfma_f32_32x32x16_bf16(af[kc], bf_, acc, 0, 0, 0);
      }
      float cn = cnorm[tt * 32 + col];
      int code = tt * 32 + col;
      #pragma unroll
      for (int r = 0; r < 16; ++r) {
        float d = fmaf(-2.f, acc[r], cn);
        if (d < best[r]) { best[r] = d; bidx[r] = code; }
      }
    }
    __syncthreads();
  }
  #pragma unroll
  for (int off = 1; off < 32; off <<= 1) {
    #pragma unroll
    for (int r = 0; r < 16; ++r) {
      float ob = __shfl_xor(best[r], off, 64);
      int   oi = __shfl_xor(bidx[r], off, 64);
      if (ob < best[r]) { best[r] = ob; bidx[r] = oi; }
    }
  }
  if (col == 0) {
    #pragma unroll
    for (int r = 0; r < 16; ++r)
      s_idx[wv][(r & 3) + 8 * (r >> 2) + 4 * khalf] = bidx[r];
  }
  __syncthreads();
  int row = lane >> 1, half2 = lane & 1;
  int m = m0 + row;
  int idx = s_idx[wv][row];
  const float4* crow = (const float4*)(cb + idx * 64 + half2 * 32);
  const float4* zp = (const float4*)(ze + (size_t)m * 64 + half2 * 32);
  uint2* zqp = (uint2*)(zq + (size_t)m * 64 + half2 * 32);
  float lsum = 0.f;
  #pragma unroll
  for (int q = 0; q < 8; ++q) {
    float4 c4 = crow[q];
    float4 z4 = zp[q];
    uint2 u; u.x = pack2bf(c4.x, c4.y); u.y = pack2bf(c4.z, c4.w);
    zqp[q] = u;
    float d;
    d = z4.x - c4.x; lsum = fmaf(d, d, lsum);
    d = z4.y - c4.y; lsum = fmaf(d, d, lsum);
    d = z4.z - c4.z; lsum = fmaf(d, d, lsum);
    d = z4.w - c4.w; lsum = fmaf(d, d, lsum);
  }
  #pragma unroll
  for (int off = 32; off > 0; off >>= 1) lsum += __shfl_down(lsum, off, 64);
  if (lane == 0) atomicAdd(acc_loss, lsum);
}

// ---------------- conv4: d2 NHWC bf16 -> x_recon NCHW fp32 (+recon loss)
// 16x16x32 MFMA, N=16 (co pad 3->16), M=64/wave; all B-frags in LDS.
__global__ __launch_bounds__(256, 2) void conv4_k(
    const unsigned short* __restrict__ in, const unsigned short* __restrict__ wb,
    const float* __restrict__ bias, const float* __restrict__ x,
    float* __restrict__ out, float* __restrict__ acc_loss,
    const unsigned short* __restrict__ zeropg) {
  __shared__ unsigned short sW[18432];   // 9 taps x 4 kc x 512 (36 KB)
  int tid = threadIdx.x, lane = tid & 63, wv = tid >> 6;
  #pragma unroll
  for (int q = 0; q < 9; ++q) {
    int i = q * 256 + tid;
    *(uint4*)&sW[i * 8] = *(const uint4*)(wb + i * 8);
  }
  int m0 = blockIdx.x * 256 + wv * 64;
  int quad = lane >> 4, mloc = lane & 15;
  int n_[4], oh_[4], ow_[4];
  #pragma unroll
  for (int s = 0; s < 4; ++s) {
    int mm = m0 + s * 16 + mloc;
    n_[s] = mm >> 14;
    int rem = mm & 16383;
    oh_[s] = rem >> 7; ow_[s] = rem & 127;
  }
  f32x4 acc[4];
  #pragma unroll
  for (int s = 0; s < 4; ++s)
    #pragma unroll
    for (int e = 0; e < 4; ++e) acc[s][e] = 0.f;
  __syncthreads();
  #pragma unroll
  for (int t = 0; t < 9; ++t) {
    int dh = t / 3 - 1, dw = t % 3 - 1;
    const unsigned short* ap[4];
    #pragma unroll
    for (int s = 0; s < 4; ++s) {
      int ih = oh_[s] + dh, iw = ow_[s] + dw;
      bool valid = ((unsigned)ih < 128u) && ((unsigned)iw < 128u);
      ap[s] = valid ? (in + ((size_t)(n_[s] * 128 + ih) * 128 + iw) * 128 + quad * 8)
                    : (zeropg + quad * 8);
    }
    #pragma unroll
    for (int kc = 0; kc < 4; ++kc) {
      short8 bf_ = *(const short8*)&sW[(t * 4 + kc) * 512 + lane * 8];
      #pragma unroll
      for (int s = 0; s < 4; ++s) {
        short8 a = *(const short8*)(ap[s] + kc * 32);
        acc[s] = __builtin_amdgcn_mfma_f32_16x16x32_bf16(a, bf_, acc[s], 0, 0, 0);
      }
    }
  }
  int co = lane & 15;
  float bv = (co < 3) ? bias[co] : 0.f;
  float lsum = 0.f;
  #pragma unroll
  for (int s = 0; s < 4; ++s)
    #pragma unroll
    for (int r = 0; r < 4; ++r) {
      int m = m0 + s * 16 + quad * 4 + r;
      if (co < 3) {
        float v = acc[s][r] + bv;
        int n2 = m >> 14, r2 = m & 16383;
        int gi = (n2 * 3 + co) * 16384 + r2;
        out[gi] = v;
        float d = v - x[gi];
        lsum = fmaf(d, d, lsum);
      }
    }
  #pragma unroll
  for (int off = 32; off > 0; off >>= 1) lsum += __shfl_down(lsum, off, 64);
  if (lane == 0) atomicAdd(acc_loss, lsum);
}

// ---------------- finalize losses
__global__ void finalize_k(const float* __restrict__ accv, float* __restrict__ out) {
  if (threadIdx.x == 0 && blockIdx.x == 0) {
    float recon = accv[0] / 3145728.0f;
    float vq = 1.25f * accv[1] / 4194304.0f;
    out[3145728] = recon + vq;
    out[3145729] = recon;
    out[3145730] = vq;
  }
}

extern "C" void kernel_launch(void* const* d_in, const int* in_sizes, int n_in,
                              void* d_out, int out_size, void* d_ws, size_t ws_size,
                              hipStream_t stream) {
  const float* x   = (const float*)d_in[0];
  const float* ew1 = (const float*)d_in[1];
  const float* eb1 = (const float*)d_in[2];
  const float* ew2 = (const float*)d_in[3];
  const float* eb2 = (const float*)d_in[4];
  const float* ew3 = (const float*)d_in[5];
  const float* eb3 = (const float*)d_in[6];
  const float* cb  = (const float*)d_in[7];
  const float* dw1 = (const float*)d_in[8];
  const float* db1 = (const float*)d_in[9];
  const float* dw2 = (const float*)d_in[10];
  const float* db2 = (const float*)d_in[11];
  const float* dw3 = (const float*)d_in[12];
  const float* db3 = (const float*)d_in[13];
  float* out = (float*)d_out;

  char* ws = (char*)d_ws;
  float* acc = (float*)ws;                               // [0]=recon ss, [1]=vq ss
  unsigned short* zeropg = (unsigned short*)(ws + 256);  // 512B zero page
  char* p = ws + 1024;
  unsigned short* wb2  = (unsigned short*)p; p += 524288;  // conv2 16*8*4*512*2
  unsigned short* wb3  = (unsigned short*)p; p += 147456;  // conv3  9*8*2*512*2
  unsigned short* wb4  = (unsigned short*)p; p += 36864;   // conv4 9*4*512*2
  unsigned short* wbd1 = (unsigned short*)p; p += 262144;  // dc1 4*4*4*4*512*2
  unsigned short* wbd2 = (unsigned short*)p; p += 524288;  // dc2 4*4*8*4*512*2
  unsigned short* cbf  = (unsigned short*)p; p += 65536;   // cb frags
  float*          cnrm = (float*)p;          p += 2048;
  size_t fixed = (size_t)(p - ws);

  // full-batch intermediates
  unsigned short* h1 = (unsigned short*)p; p += 67108864ull;  // h1 / d1 slot
  unsigned short* h2 = (unsigned short*)p; p += 16777216ull;
  float*          ze = (float*)p;          p += 16777216ull;
  unsigned short* zq = (unsigned short*)p; p += 8388608ull;
  unsigned short* d2 = (unsigned short*)p;
  size_t base = fixed + 67108864ull + 16777216ull + 16777216ull + 8388608ull;
  int CD = 64;
  while (CD > 1 && base + (size_t)CD * 4194304ull > ws_size) CD >>= 1;

  hipMemsetAsync(ws, 0, 1024, stream);   // loss accumulators + zero page
  repack_conv_w<128, 16, 4><<<(16 * 8 * 4 * 512 + 255) / 256, 256, 0, stream>>>(ew2, wb2, 128);
  repack_conv_w<128, 9, 2><<<(9 * 8 * 2 * 512 + 255) / 256, 256, 0, stream>>>(ew3, wb3, 64);
  repack_conv4_w<<<(9 * 4 * 512 + 255) / 256, 256, 0, stream>>>(dw3, wb4);
  repack_deconv_w<64, 128, 4><<<(16 * 4 * 4 * 512 + 255) / 256, 256, 0, stream>>>(dw1, wbd1);
  repack_deconv_w<128, 128, 4><<<(16 * 8 * 4 * 512 + 255) / 256, 256, 0, stream>>>(dw2, wbd2);
  repack_cb<<<128, 256, 0, stream>>>(cb, cbf);
  cnorm_k<<<2, 256, 0, stream>>>(cb, cnrm);

  // ---- encoder, full batch ----
  conv1_k<<<64 * 512, 256, 0, stream>>>(x, ew1, eb1, h1);
  // conv2: M=65536, S=4 -> 128 mblocks, cog 2
  mconv_k<128, 128, 4, 2, 4, 64, 64, 32, 32, 16, 4, 2, false, true, false>
      <<<dim3(128, 1, 2), 256, 0, stream>>>(h1, wb2, eb2, h2, zeropg);
  // conv3: M=65536, S=2 -> 256 mblocks, cog 1 (NT=2 covers CO=64)
  mconv_k<128, 64, 2, 2, 2, 32, 32, 32, 32, 9, 3, 1, false, false, true>
      <<<dim3(256, 1, 1), 256, 0, stream>>>(h2, wb3, eb3, ze, zeropg);
  vq2_k<<<512, 256, 0, stream>>>(ze, cb, cbf, cnrm, zq, acc + 1);
  // dc1: M=65536, S=4 -> 128 mblocks, 4 cls, cog 2
  mconv_k<64, 128, 4, 2, 4, 32, 32, 32, 32, 4, 2, 1, true, true, false>
      <<<dim3(128, 4, 2), 256, 0, stream>>>(zq, wbd1, db1, h1, zeropg);

  // ---- decoder, chunked over d2 ----
  for (int n0 = 0; n0 < 64; n0 += CD) {
    const unsigned short* d1c = h1 + (size_t)n0 * 524288;   // 64*64*128
    mconv_k<128, 128, 4, 2, 4, 64, 64, 64, 64, 4, 2, 1, true, true, false>
        <<<dim3(CD * 8, 4, 2), 256, 0, stream>>>(d1c, wbd2, db2, d2, zeropg);
    conv4_k<<<CD * 64, 256, 0, stream>>>(d2, wb4, db3, x + (size_t)n0 * 49152,
                                         out + (size_t)n0 * 49152, acc, zeropg);
  }
  finalize_k<<<1, 64, 0, stream>>>(acc, out);
}

// Round 6
// 1102.971 us; speedup vs baseline: 13.3183x; 1.2528x over previous
//
#include <hip/hip_runtime.h>
#include <hip/hip_bf16.h>

// ---- VQ-VAE forward, round 6 ----------------------------------------------
// r5 diagnosis: conv1_k top dispatch (371us, 27%) -- LDS-inst-throughput
// bound: 4 outputs/thread but 96 LDS reads/thread; plus uncoalesced
// stride-48 weight staging per 32768 blocks. r6: conv1 rewritten --
// weights pre-transposed once ([tap][co] fp32), block = 4 oh rows (grid
// 1024), thread = 128 outputs (4oh x 16co x 2cob), per-tap 4 b128 w-reads
// (2-way alias = free) + 4 broadcast x reads for 64 FMA -> VALU/LDS
// balanced, ~50us. All other kernels unchanged from r5.
// Layouts (HW-verified): 32x32x16_bf16 A[m=lane&31][k=(lane>>5)*8+j],
//   D: col=lane&31, row=(reg&3)+8*(reg>>2)+4*(lane>>5).
// 16x16x32_bf16 A[m=lane&15][k=(lane>>4)*8+j], D: col=lane&15,
//   row=(lane>>4)*4+reg.
// Deconv k4s2p1 parity (a,b): out(2q+a,2r+b) += in(q+a-i, r+b-j)*
//   w[ci][co][2i+1-a][2j+1-b]  (verified r2-r5).

typedef __attribute__((ext_vector_type(8))) short short8;
typedef __attribute__((ext_vector_type(16))) float f32x16;
typedef __attribute__((ext_vector_type(4))) float f32x4;

__device__ __forceinline__ unsigned short f2bf(float f) {
  union { __hip_bfloat16 b; unsigned short u; } cv;
  cv.b = __float2bfloat16(f);
  return cv.u;
}
__device__ __forceinline__ unsigned pack2bf(float a, float b) {
  return (unsigned)f2bf(a) | ((unsigned)f2bf(b) << 16);
}

// ---------------- weight repack: conv layers  w[CO][CI][NTAP] fp32 -> frags
// layout: [tap][kc][ntall][lane][8]
template<int CI, int NTAP, int NTALL>
__global__ void repack_conv_w(const float* __restrict__ w,
                              unsigned short* __restrict__ wb, int co_real) {
  const int KC = CI / 16;
  const int total = NTAP * KC * NTALL * 512;
  int i = blockIdx.x * 256 + threadIdx.x;
  if (i >= total) return;
  int j = i & 7, lane = (i >> 3) & 63, t2 = i >> 9;
  int nt = t2 % NTALL; t2 /= NTALL;
  int kc = t2 % KC; int tap = t2 / KC;
  int co = nt * 32 + (lane & 31);
  int ci = kc * 16 + (lane >> 5) * 8 + j;
  float v = (co < co_real) ? w[(co * CI + ci) * NTAP + tap] : 0.f;
  wb[i] = f2bf(v);
}

// ---------------- weight repack: deconv  w[CI][CO][4][4] fp32 -> frags/class
// layout: [cls][tap][kc][ntall][lane][8]
template<int CI, int CO, int NTALL>
__global__ void repack_deconv_w(const float* __restrict__ w,
                                unsigned short* __restrict__ wb) {
  const int KC = CI / 16;
  const int total = 16 * KC * NTALL * 512;
  int i = blockIdx.x * 256 + threadIdx.x;
  if (i >= total) return;
  int j = i & 7, lane = (i >> 3) & 63, t2 = i >> 9;
  int nt = t2 % NTALL; t2 /= NTALL;
  int kc = t2 % KC; t2 /= KC;
  int tap = t2 & 3, cls = t2 >> 2;
  int a = cls >> 1, b = cls & 1, ti = tap >> 1, tj = tap & 1;
  int kh = 2 * ti + 1 - a, kw = 2 * tj + 1 - b;
  int co = nt * 32 + (lane & 31);
  int ci = kc * 16 + (lane >> 5) * 8 + j;
  wb[i] = f2bf(w[((ci * CO + co) * 4 + kh) * 4 + kw]);
}

// ---------------- weight repack: conv4 16x16 frags  dw3[3][128][3][3]
__global__ void repack_conv4_w(const float* __restrict__ w,
                               unsigned short* __restrict__ wb) {
  const int total = 9 * 4 * 512;
  int i = blockIdx.x * 256 + threadIdx.x;
  if (i >= total) return;
  int j = i & 7, lane = (i >> 3) & 63, tk = i >> 9;
  int kc = tk & 3, t = tk >> 2;
  int co = lane & 15;
  int ci = kc * 32 + (lane >> 4) * 8 + j;
  float v = (co < 3) ? w[(co * 128 + ci) * 9 + t] : 0.f;
  wb[i] = f2bf(v);
}

// ---------------- weight repack: conv1  ew1[128][3][4][4] -> wc1[tap*128+co] fp32
__global__ void repack_conv1_w(const float* __restrict__ w,
                               float* __restrict__ wc1) {
  int i = blockIdx.x * 256 + threadIdx.x;   // 6144
  if (i >= 6144) return;
  int tap = i >> 7, co = i & 127;
  wc1[i] = w[co * 48 + tap];
}

// ---------------- codebook repack -> bf16 B-frags [tile16][kc4][lane64][8]
__global__ void repack_cb(const float* __restrict__ cb,
                          unsigned short* __restrict__ cbf) {
  int i = blockIdx.x * 256 + threadIdx.x;   // 32768
  int j = i & 7, lane = (i >> 3) & 63;
  int kc = (i >> 9) & 3, tile = i >> 11;
  int code = tile * 32 + (lane & 31);
  int d = kc * 16 + (lane >> 5) * 8 + j;
  cbf[i] = f2bf(cb[code * 64 + d]);
}
__global__ void cnorm_k(const float* __restrict__ cb, float* __restrict__ cn) {
  int k = blockIdx.x * 256 + threadIdx.x;
  if (k >= 512) return;
  const float4* r = (const float4*)(cb + k * 64);
  float s = 0.f;
  #pragma unroll
  for (int q = 0; q < 16; ++q) {
    float4 v = r[q];
    s = fmaf(v.x, v.x, s); s = fmaf(v.y, v.y, s);
    s = fmaf(v.z, v.z, s); s = fmaf(v.w, v.w, s);
  }
  cn[k] = s;
}

// ---------------- conv1 v2: x NCHW fp32 [64,3,128,128] -> h1 NHWC bf16
// Block = (n, oh-quad). Thread = (ow, cg): 4 oh x 16 co x 2 cob = 128 out.
__global__ __launch_bounds__(256, 4) void conv1_k(
    const float* __restrict__ x, const float* __restrict__ wc1,
    const float* __restrict__ bias, unsigned short* __restrict__ out) {
  __shared__ float swc[6144];          // [tap][co] 24 KB
  __shared__ float sx[3 * 10 * 132];   // [ci][r][c] 15.8 KB
  int tid = threadIdx.x;
  int n = blockIdx.x >> 4, ohq = blockIdx.x & 15;
  #pragma unroll
  for (int q = 0; q < 6; ++q) {
    int i = (q * 256 + tid) * 4;
    *(float4*)&swc[i] = *(const float4*)&wc1[i];
  }
  int ihb = 8 * ohq - 1;
  for (int i = tid; i < 3960; i += 256) {
    int ci = i / 1320, rem = i - ci * 1320;
    int r = rem / 132, c = rem - r * 132;
    int ih = ihb + r, iw = c - 1;
    float v = 0.f;
    if ((unsigned)ih < 128u && (unsigned)iw < 128u)
      v = x[(n * 3 + ci) * 16384 + ih * 128 + iw];
    sx[i] = v;
  }
  __syncthreads();
  int ow = tid >> 2, cg = tid & 3;
  #pragma unroll
  for (int cob = 0; cob < 2; ++cob) {
    int co0 = cob * 64 + cg * 16;
    float4 acc[4][4];
    float4 bq[4];
    #pragma unroll
    for (int q = 0; q < 4; ++q) bq[q] = *(const float4*)&bias[co0 + q * 4];
    #pragma unroll
    for (int o = 0; o < 4; ++o)
      #pragma unroll
      for (int q = 0; q < 4; ++q) acc[o][q] = bq[q];
    for (int ci = 0; ci < 3; ++ci)
      for (int kh = 0; kh < 4; ++kh) {
        #pragma unroll
        for (int kw = 0; kw < 4; ++kw) {
          int tap = ci * 16 + kh * 4 + kw;
          const float* wp = &swc[tap * 128 + co0];
          float4 w0 = *(const float4*)(wp);
          float4 w1 = *(const float4*)(wp + 4);
          float4 w2 = *(const float4*)(wp + 8);
          float4 w3 = *(const float4*)(wp + 12);
          const float* xp = &sx[ci * 1320 + kh * 132 + 2 * ow + kw];
          #pragma unroll
          for (int o = 0; o < 4; ++o) {
            float xv = xp[o * 264];   // row r = 2*o + kh
            acc[o][0].x = fmaf(xv, w0.x, acc[o][0].x);
            acc[o][0].y = fmaf(xv, w0.y, acc[o][0].y);
            acc[o][0].z = fmaf(xv, w0.z, acc[o][0].z);
            acc[o][0].w = fmaf(xv, w0.w, acc[o][0].w);
            acc[o][1].x = fmaf(xv, w1.x, acc[o][1].x);
            acc[o][1].y = fmaf(xv, w1.y, acc[o][1].y);
            acc[o][1].z = fmaf(xv, w1.z, acc[o][1].z);
            acc[o][1].w = fmaf(xv, w1.w, acc[o][1].w);
            acc[o][2].x = fmaf(xv, w2.x, acc[o][2].x);
            acc[o][2].y = fmaf(xv, w2.y, acc[o][2].y);
            acc[o][2].z = fmaf(xv, w2.z, acc[o][2].z);
            acc[o][2].w = fmaf(xv, w2.w, acc[o][2].w);
            acc[o][3].x = fmaf(xv, w3.x, acc[o][3].x);
            acc[o][3].y = fmaf(xv, w3.y, acc[o][3].y);
            acc[o][3].z = fmaf(xv, w3.z, acc[o][3].z);
            acc[o][3].w = fmaf(xv, w3.w, acc[o][3].w);
          }
        }
      }
    #pragma unroll
    for (int o = 0; o < 4; ++o) {
      int oh = ohq * 4 + o;
      unsigned short* op = out + ((size_t)(n * 64 + oh) * 64 + ow) * 128 + co0;
      uint4 u0, u1;
      u0.x = pack2bf(fmaxf(acc[o][0].x, 0.f), fmaxf(acc[o][0].y, 0.f));
      u0.y = pack2bf(fmaxf(acc[o][0].z, 0.f), fmaxf(acc[o][0].w, 0.f));
      u0.z = pack2bf(fmaxf(acc[o][1].x, 0.f), fmaxf(acc[o][1].y, 0.f));
      u0.w = pack2bf(fmaxf(acc[o][1].z, 0.f), fmaxf(acc[o][1].w, 0.f));
      u1.x = pack2bf(fmaxf(acc[o][2].x, 0.f), fmaxf(acc[o][2].y, 0.f));
      u1.y = pack2bf(fmaxf(acc[o][2].z, 0.f), fmaxf(acc[o][2].w, 0.f));
      u1.z = pack2bf(fmaxf(acc[o][3].x, 0.f), fmaxf(acc[o][3].y, 0.f));
      u1.w = pack2bf(fmaxf(acc[o][3].z, 0.f), fmaxf(acc[o][3].w, 0.f));
      *(uint4*)(op) = u0;
      *(uint4*)(op + 8) = u1;
    }
  }
}

// ---------------- generic MFMA conv / parity-deconv
// M = 32*S per wave, N = 32*NT per wave (co-group = blockIdx.z).
// B-frags double-buffered in LDS per tap, prefetched via registers.
template<int CI, int CO, int NTALL, int NT, int S, int IH, int IW, int OH, int OW,
         int NTAP, int KW, int STRIDE, bool DECONV, bool RELU, bool F32OUT>
__global__ __launch_bounds__(256, 2) void mconv_k(
    const unsigned short* __restrict__ in, const unsigned short* __restrict__ wb,
    const float* __restrict__ bias, void* __restrict__ outv,
    const unsigned short* __restrict__ zeropg) {
  const int KC = CI / 16;
  const int TSZ = KC * NT * 512;       // shorts per staged tap slice
  const int STG = KC * NT / 4;         // uint4 per thread per stage
  __shared__ unsigned short sB[2][TSZ];
  int tid = threadIdx.x, lane = tid & 63, wv = tid >> 6;
  int m0 = blockIdx.x * (128 * S) + wv * (32 * S);
  int cls = DECONV ? blockIdx.y : 0;
  int cog = blockIdx.z;
  int ca = cls >> 1, cb2 = cls & 1;
  int khalf = lane >> 5;
  int n_[S], oh_[S], ow_[S];
  #pragma unroll
  for (int s = 0; s < S; ++s) {
    int mm = m0 + s * 32 + (lane & 31);
    n_[s] = mm / (OH * OW);
    int rem = mm % (OH * OW);
    oh_[s] = rem / OW; ow_[s] = rem % OW;
  }
  f32x16 acc[S][NT];
  #pragma unroll
  for (int s = 0; s < S; ++s)
    #pragma unroll
    for (int t = 0; t < NT; ++t)
      #pragma unroll
      for (int e = 0; e < 16; ++e) acc[s][t][e] = 0.f;

  const unsigned short* wcls = wb + (size_t)cls * NTAP * KC * NTALL * 512;
  uint4 st[STG];
  // prologue: stage tap 0 into buf 0
  #pragma unroll
  for (int q = 0; q < STG; ++q) {
    int i = q * 256 + tid;
    int kc = i / (NT * 64), r = i - kc * (NT * 64);
    st[q] = *(const uint4*)(wcls + (size_t)(kc * NTALL + cog * NT) * 512 + r * 8);
  }
  #pragma unroll
  for (int q = 0; q < STG; ++q) {
    int i = q * 256 + tid;
    *(uint4*)&sB[0][i * 8] = st[q];
  }
  __syncthreads();

  for (int t = 0; t < NTAP; ++t) {
    int cur = t & 1;
    if (t + 1 < NTAP) {
      const unsigned short* wt = wcls + (size_t)(t + 1) * KC * NTALL * 512;
      #pragma unroll
      for (int q = 0; q < STG; ++q) {
        int i = q * 256 + tid;
        int kc = i / (NT * 64), r = i - kc * (NT * 64);
        st[q] = *(const uint4*)(wt + (size_t)(kc * NTALL + cog * NT) * 512 + r * 8);
      }
    }
    // A pointers for this tap
    const unsigned short* ap[S];
    #pragma unroll
    for (int s = 0; s < S; ++s) {
      int ih, iw;
      if (DECONV) { ih = oh_[s] + ca - (t >> 1); iw = ow_[s] + cb2 - (t & 1); }
      else        { ih = STRIDE * oh_[s] - 1 + t / KW; iw = STRIDE * ow_[s] - 1 + t % KW; }
      bool valid = ((unsigned)ih < (unsigned)IH) && ((unsigned)iw < (unsigned)IW);
      ap[s] = valid ? (in + ((size_t)(n_[s] * IH + ih) * IW + iw) * CI + khalf * 8)
                    : (zeropg + khalf * 8);
    }
    #pragma unroll
    for (int kc = 0; kc < KC; ++kc) {
      short8 a[S];
      #pragma unroll
      for (int s = 0; s < S; ++s) a[s] = *(const short8*)(ap[s] + kc * 16);
      #pragma unroll
      for (int nt = 0; nt < NT; ++nt) {
        short8 b = *(const short8*)&sB[cur][(kc * NT + nt) * 512 + lane * 8];
        #pragma unroll
        for (int s = 0; s < S; ++s)
          acc[s][nt] = __builtin_amdgcn_mfma_f32_32x32x16_bf16(a[s], b, acc[s][nt], 0, 0, 0);
      }
    }
    if (t + 1 < NTAP) {
      #pragma unroll
      for (int q = 0; q < STG; ++q) {
        int i = q * 256 + tid;
        *(uint4*)&sB[cur ^ 1][i * 8] = st[q];
      }
    }
    __syncthreads();
  }

  int col = lane & 31;
  #pragma unroll
  for (int s = 0; s < S; ++s)
    #pragma unroll
    for (int nt = 0; nt < NT; ++nt) {
      int co = (cog * NT + nt) * 32 + col;
      float bv = bias[co];
      #pragma unroll
      for (int r = 0; r < 16; ++r) {
        int mrow = (r & 3) + 8 * (r >> 2) + 4 * khalf;
        int mp = m0 + s * 32 + mrow;
        int n2 = mp / (OH * OW), r2 = mp % (OH * OW);
        int oh2 = r2 / OW, ow2 = r2 % OW;
        float v = acc[s][nt][r] + bv;
        if (RELU) v = fmaxf(v, 0.f);
        size_t idx;
        if (DECONV)
          idx = ((size_t)(n2 * (2 * OH) + 2 * oh2 + ca) * (2 * OW) + 2 * ow2 + cb2) * CO + co;
        else
          idx = ((size_t)(n2 * OH + oh2) * OW + ow2) * CO + co;
        if (F32OUT) ((float*)outv)[idx] = v;
        else        ((unsigned short*)outv)[idx] = f2bf(v);
      }
    }
}

// ---------------- VQ via MFMA, codebook frags staged in LDS (2 phases x 32KB)
__global__ __launch_bounds__(256, 2) void vq2_k(
    const float* __restrict__ ze, const float* __restrict__ cb,
    const unsigned short* __restrict__ cbf, const float* __restrict__ cnorm,
    unsigned short* __restrict__ zq, float* __restrict__ acc_loss) {
  __shared__ unsigned short sC[16384];   // 8 tiles of B-frags (32 KB)
  __shared__ int s_idx[4][32];
  int tid = threadIdx.x, lane = tid & 63, wv = tid >> 6;
  int m0 = blockIdx.x * 128 + wv * 32;
  int col = lane & 31, khalf = lane >> 5;
  const float* zrow = ze + (size_t)(m0 + col) * 64 + khalf * 8;
  short8 af[4];
  #pragma unroll
  for (int kc = 0; kc < 4; ++kc) {
    float4 a = *(const float4*)(zrow + kc * 16);
    float4 b = *(const float4*)(zrow + kc * 16 + 4);
    short8 f;
    f[0] = (short)f2bf(a.x); f[1] = (short)f2bf(a.y);
    f[2] = (short)f2bf(a.z); f[3] = (short)f2bf(a.w);
    f[4] = (short)f2bf(b.x); f[5] = (short)f2bf(b.y);
    f[6] = (short)f2bf(b.z); f[7] = (short)f2bf(b.w);
    af[kc] = f;
  }
  float best[16]; int bidx[16];
  #pragma unroll
  for (int r = 0; r < 16; ++r) { best[r] = 3.4e38f; bidx[r] = 0; }
  for (int half = 0; half < 2; ++half) {
    #pragma unroll
    for (int q = 0; q < 8; ++q) {
      int i = q * 256 + tid;
      *(uint4*)&sC[i * 8] = *(const uint4*)(cbf + half * 16384 + i * 8);
    }
    __syncthreads();
    #pragma unroll
    for (int t8 = 0; t8 < 8; ++t8) {
      int tt = half * 8 + t8;
      f32x16 acc;
      #pragma unroll
      for (int e = 0; e < 16; ++e) acc[e] = 0.f;
      #pragma unroll
      for (int kc = 0; kc < 4; ++kc) {
        short8 bf_ = *(const short8*)&sC[(t8 * 4 + kc) * 512 + lane * 8];
        acc = __builtin_amdgcn_mfma_f32_32x32x16_bf16(af[kc], bf_, acc, 0, 0, 0);
      }
      float cn = cnorm[tt * 32 + col];
      int code = tt * 32 + col;
      #pragma unroll
      for (int r = 0; r < 16; ++r) {
        float d = fmaf(-2.f, acc[r], cn);
        if (d < best[r]) { best[r] = d; bidx[r] = code; }
      }
    }
    __syncthreads();
  }
  #pragma unroll
  for (int off = 1; off < 32; off <<= 1) {
    #pragma unroll
    for (int r = 0; r < 16; ++r) {
      float ob = __shfl_xor(best[r], off, 64);
      int   oi = __shfl_xor(bidx[r], off, 64);
      if (ob < best[r]) { best[r] = ob; bidx[r] = oi; }
    }
  }
  if (col == 0) {
    #pragma unroll
    for (int r = 0; r < 16; ++r)
      s_idx[wv][(r & 3) + 8 * (r >> 2) + 4 * khalf] = bidx[r];
  }
  __syncthreads();
  int row = lane >> 1, half2 = lane & 1;
  int m = m0 + row;
  int idx = s_idx[wv][row];
  const float4* crow = (const float4*)(cb + idx * 64 + half2 * 32);
  const float4* zp = (const float4*)(ze + (size_t)m * 64 + half2 * 32);
  uint2* zqp = (uint2*)(zq + (size_t)m * 64 + half2 * 32);
  float lsum = 0.f;
  #pragma unroll
  for (int q = 0; q < 8; ++q) {
    float4 c4 = crow[q];
    float4 z4 = zp[q];
    uint2 u; u.x = pack2bf(c4.x, c4.y); u.y = pack2bf(c4.z, c4.w);
    zqp[q] = u;
    float d;
    d = z4.x - c4.x; lsum = fmaf(d, d, lsum);
    d = z4.y - c4.y; lsum = fmaf(d, d, lsum);
    d = z4.z - c4.z; lsum = fmaf(d, d, lsum);
    d = z4.w - c4.w; lsum = fmaf(d, d, lsum);
  }
  #pragma unroll
  for (int off = 32; off > 0; off >>= 1) lsum += __shfl_down(lsum, off, 64);
  if (lane == 0) atomicAdd(acc_loss, lsum);
}

// ---------------- conv4: d2 NHWC bf16 -> x_recon NCHW fp32 (+recon loss)
// 16x16x32 MFMA, N=16 (co pad 3->16), M=64/wave; all B-frags in LDS.
__global__ __launch_bounds__(256, 2) void conv4_k(
    const unsigned short* __restrict__ in, const unsigned short* __restrict__ wb,
    const float* __restrict__ bias, const float* __restrict__ x,
    float* __restrict__ out, float* __restrict__ acc_loss,
    const unsigned short* __restrict__ zeropg) {
  __shared__ unsigned short sW[18432];   // 9 taps x 4 kc x 512 (36 KB)
  int tid = threadIdx.x, lane = tid & 63, wv = tid >> 6;
  #pragma unroll
  for (int q = 0; q < 9; ++q) {
    int i = q * 256 + tid;
    *(uint4*)&sW[i * 8] = *(const uint4*)(wb + i * 8);
  }
  int m0 = blockIdx.x * 256 + wv * 64;
  int quad = lane >> 4, mloc = lane & 15;
  int n_[4], oh_[4], ow_[4];
  #pragma unroll
  for (int s = 0; s < 4; ++s) {
    int mm = m0 + s * 16 + mloc;
    n_[s] = mm >> 14;
    int rem = mm & 16383;
    oh_[s] = rem >> 7; ow_[s] = rem & 127;
  }
  f32x4 acc[4];
  #pragma unroll
  for (int s = 0; s < 4; ++s)
    #pragma unroll
    for (int e = 0; e < 4; ++e) acc[s][e] = 0.f;
  __syncthreads();
  #pragma unroll
  for (int t = 0; t < 9; ++t) {
    int dh = t / 3 - 1, dw = t % 3 - 1;
    const unsigned short* ap[4];
    #pragma unroll
    for (int s = 0; s < 4; ++s) {
      int ih = oh_[s] + dh, iw = ow_[s] + dw;
      bool valid = ((unsigned)ih < 128u) && ((unsigned)iw < 128u);
      ap[s] = valid ? (in + ((size_t)(n_[s] * 128 + ih) * 128 + iw) * 128 + quad * 8)
                    : (zeropg + quad * 8);
    }
    #pragma unroll
    for (int kc = 0; kc < 4; ++kc) {
      short8 bf_ = *(const short8*)&sW[(t * 4 + kc) * 512 + lane * 8];
      #pragma unroll
      for (int s = 0; s < 4; ++s) {
        short8 a = *(const short8*)(ap[s] + kc * 32);
        acc[s] = __builtin_amdgcn_mfma_f32_16x16x32_bf16(a, bf_, acc[s], 0, 0, 0);
      }
    }
  }
  int co = lane & 15;
  float bv = (co < 3) ? bias[co] : 0.f;
  float lsum = 0.f;
  #pragma unroll
  for (int s = 0; s < 4; ++s)
    #pragma unroll
    for (int r = 0; r < 4; ++r) {
      int m = m0 + s * 16 + quad * 4 + r;
      if (co < 3) {
        float v = acc[s][r] + bv;
        int n2 = m >> 14, r2 = m & 16383;
        int gi = (n2 * 3 + co) * 16384 + r2;
        out[gi] = v;
        float d = v - x[gi];
        lsum = fmaf(d, d, lsum);
      }
    }
  #pragma unroll
  for (int off = 32; off > 0; off >>= 1) lsum += __shfl_down(lsum, off, 64);
  if (lane == 0) atomicAdd(acc_loss, lsum);
}

// ---------------- finalize losses
__global__ void finalize_k(const float* __restrict__ accv, float* __restrict__ out) {
  if (threadIdx.x == 0 && blockIdx.x == 0) {
    float recon = accv[0] / 3145728.0f;
    float vq = 1.25f * accv[1] / 4194304.0f;
    out[3145728] = recon + vq;
    out[3145729] = recon;
    out[3145730] = vq;
  }
}

extern "C" void kernel_launch(void* const* d_in, const int* in_sizes, int n_in,
                              void* d_out, int out_size, void* d_ws, size_t ws_size,
                              hipStream_t stream) {
  const float* x   = (const float*)d_in[0];
  const float* ew1 = (const float*)d_in[1];
  const float* eb1 = (const float*)d_in[2];
  const float* ew2 = (const float*)d_in[3];
  const float* eb2 = (const float*)d_in[4];
  const float* ew3 = (const float*)d_in[5];
  const float* eb3 = (const float*)d_in[6];
  const float* cb  = (const float*)d_in[7];
  const float* dw1 = (const float*)d_in[8];
  const float* db1 = (const float*)d_in[9];
  const float* dw2 = (const float*)d_in[10];
  const float* db2 = (const float*)d_in[11];
  const float* dw3 = (const float*)d_in[12];
  const float* db3 = (const float*)d_in[13];
  float* out = (float*)d_out;

  char* ws = (char*)d_ws;
  float* acc = (float*)ws;                               // [0]=recon ss, [1]=vq ss
  unsigned short* zeropg = (unsigned short*)(ws + 256);  // 512B zero page
  char* p = ws + 1024;
  unsigned short* wb2  = (unsigned short*)p; p += 524288;  // conv2 16*8*4*512*2
  unsigned short* wb3  = (unsigned short*)p; p += 147456;  // conv3  9*8*2*512*2
  unsigned short* wb4  = (unsigned short*)p; p += 36864;   // conv4 9*4*512*2
  unsigned short* wbd1 = (unsigned short*)p; p += 262144;  // dc1 4*4*4*4*512*2
  unsigned short* wbd2 = (unsigned short*)p; p += 524288;  // dc2 4*4*8*4*512*2
  unsigned short* cbf  = (unsigned short*)p; p += 65536;   // cb frags
  float*          cnrm = (float*)p;          p += 2048;
  float*          wc1  = (float*)p;          p += 24576;   // conv1 [tap][co] fp32
  size_t fixed = (size_t)(p - ws);

  // full-batch intermediates
  unsigned short* h1 = (unsigned short*)p; p += 67108864ull;  // h1 / d1 slot
  unsigned short* h2 = (unsigned short*)p; p += 16777216ull;
  float*          ze = (float*)p;          p += 16777216ull;
  unsigned short* zq = (unsigned short*)p; p += 8388608ull;
  unsigned short* d2 = (unsigned short*)p;
  size_t base = fixed + 67108864ull + 16777216ull + 16777216ull + 8388608ull;
  int CD = 64;
  while (CD > 1 && base + (size_t)CD * 4194304ull > ws_size) CD >>= 1;

  hipMemsetAsync(ws, 0, 1024, stream);   // loss accumulators + zero page
  repack_conv_w<128, 16, 4><<<(16 * 8 * 4 * 512 + 255) / 256, 256, 0, stream>>>(ew2, wb2, 128);
  repack_conv_w<128, 9, 2><<<(9 * 8 * 2 * 512 + 255) / 256, 256, 0, stream>>>(ew3, wb3, 64);
  repack_conv4_w<<<(9 * 4 * 512 + 255) / 256, 256, 0, stream>>>(dw3, wb4);
  repack_deconv_w<64, 128, 4><<<(16 * 4 * 4 * 512 + 255) / 256, 256, 0, stream>>>(dw1, wbd1);
  repack_deconv_w<128, 128, 4><<<(16 * 8 * 4 * 512 + 255) / 256, 256, 0, stream>>>(dw2, wbd2);
  repack_cb<<<128, 256, 0, stream>>>(cb, cbf);
  cnorm_k<<<2, 256, 0, stream>>>(cb, cnrm);
  repack_conv1_w<<<24, 256, 0, stream>>>(ew1, wc1);

  // ---- encoder, full batch ----
  conv1_k<<<1024, 256, 0, stream>>>(x, wc1, eb1, h1);
  // conv2: M=65536, S=4 -> 128 mblocks, cog 2
  mconv_k<128, 128, 4, 2, 4, 64, 64, 32, 32, 16, 4, 2, false, true, false>
      <<<dim3(128, 1, 2), 256, 0, stream>>>(h1, wb2, eb2, h2, zeropg);
  // conv3: M=65536, S=2 -> 256 mblocks, cog 1 (NT=2 covers CO=64)
  mconv_k<128, 64, 2, 2, 2, 32, 32, 32, 32, 9, 3, 1, false, false, true>
      <<<dim3(256, 1, 1), 256, 0, stream>>>(h2, wb3, eb3, ze, zeropg);
  vq2_k<<<512, 256, 0, stream>>>(ze, cb, cbf, cnrm, zq, acc + 1);
  // dc1: M=65536, S=4 -> 128 mblocks, 4 cls, cog 2
  mconv_k<64, 128, 4, 2, 4, 32, 32, 32, 32, 4, 2, 1, true, true, false>
      <<<dim3(128, 4, 2), 256, 0, stream>>>(zq, wbd1, db1, h1, zeropg);

  // ---- decoder, chunked over d2 ----
  for (int n0 = 0; n0 < 64; n0 += CD) {
    const unsigned short* d1c = h1 + (size_t)n0 * 524288;   // 64*64*128
    mconv_k<128, 128, 4, 2, 4, 64, 64, 64, 64, 4, 2, 1, true, true, false>
        <<<dim3(CD * 8, 4, 2), 256, 0, stream>>>(d1c, wbd2, db2, d2, zeropg);
    conv4_k<<<CD * 64, 256, 0, stream>>>(d2, wb4, db3, x + (size_t)n0 * 49152,
                                         out + (size_t)n0 * 49152, acc, zeropg);
  }
  finalize_k<<<1, 64, 0, stream>>>(acc, out);
}